// Round 1
// baseline (2830.840 us; speedup 1.0000x reference)
//
#include <hip/hip_runtime.h>
#include <math.h>

#define NQR 1024
#define CDIM 256
#define SROWS 21504

// ---------------- LayerNorm: one wave per 256-wide row ----------------
__global__ __launch_bounds__(256) void ln_kernel(
    const float* __restrict__ x, const float* __restrict__ w,
    const float* __restrict__ b, float* __restrict__ y) {
  int lane = threadIdx.x & 63;
  int row = (blockIdx.x << 2) + (threadIdx.x >> 6);
  float4 v = ((const float4*)(x + (size_t)row * CDIM))[lane];
  float s = v.x + v.y + v.z + v.w;
  float ss = v.x * v.x + v.y * v.y + v.z * v.z + v.w * v.w;
#pragma unroll
  for (int off = 32; off; off >>= 1) {
    s += __shfl_xor(s, off);
    ss += __shfl_xor(ss, off);
  }
  float m = s * (1.0f / 256.0f);
  float var = ss * (1.0f / 256.0f) - m * m;
  float r = rsqrtf(var + 1e-5f);
  float4 wv = ((const float4*)w)[lane];
  float4 bv = ((const float4*)b)[lane];
  float4 o;
  o.x = (v.x - m) * r * wv.x + bv.x;
  o.y = (v.y - m) * r * wv.y + bv.y;
  o.z = (v.z - m) * r * wv.z + bv.z;
  o.w = (v.w - m) * r * wv.w + bv.w;
  ((float4*)(y + (size_t)row * CDIM))[lane] = o;
}

// ---------------- Generic fp32 GEMM: C[M,N] = A[M,K] @ W[N,K]^T + bias (+res, +gelu) ----
// M%64==0, N%64==0, K%16==0. 64x64 tile, 256 threads, 4x4 microtile.
template <bool GELU, bool RES>
__global__ __launch_bounds__(256) void gemm_kernel(
    const float* __restrict__ A, const float* __restrict__ W,
    const float* __restrict__ bias, const float* __restrict__ res,
    float* __restrict__ C, int M, int N, int K) {
  __shared__ float As[16][64];
  __shared__ float Bs[16][64];
  int t = threadIdx.x;
  int tx = t & 15, ty = t >> 4;
  int arow = t >> 2;
  int acol = (t & 3) << 2;
  const float* Ap = A + (size_t)(blockIdx.x * 64 + arow) * K + acol;
  const float* Wp = W + (size_t)(blockIdx.y * 64 + arow) * K + acol;
  float acc[4][4] = {};
  for (int k0 = 0; k0 < K; k0 += 16) {
    float4 av = *(const float4*)(Ap + k0);
    float4 wv = *(const float4*)(Wp + k0);
    __syncthreads();
    As[acol + 0][arow] = av.x;
    As[acol + 1][arow] = av.y;
    As[acol + 2][arow] = av.z;
    As[acol + 3][arow] = av.w;
    Bs[acol + 0][arow] = wv.x;
    Bs[acol + 1][arow] = wv.y;
    Bs[acol + 2][arow] = wv.z;
    Bs[acol + 3][arow] = wv.w;
    __syncthreads();
#pragma unroll
    for (int kk = 0; kk < 16; kk++) {
      float4 a = *(const float4*)(&As[kk][ty << 2]);
      float4 bb = *(const float4*)(&Bs[kk][tx << 2]);
      acc[0][0] += a.x * bb.x; acc[0][1] += a.x * bb.y; acc[0][2] += a.x * bb.z; acc[0][3] += a.x * bb.w;
      acc[1][0] += a.y * bb.x; acc[1][1] += a.y * bb.y; acc[1][2] += a.y * bb.z; acc[1][3] += a.y * bb.w;
      acc[2][0] += a.z * bb.x; acc[2][1] += a.z * bb.y; acc[2][2] += a.z * bb.z; acc[2][3] += a.z * bb.w;
      acc[3][0] += a.w * bb.x; acc[3][1] += a.w * bb.y; acc[3][2] += a.w * bb.z; acc[3][3] += a.w * bb.w;
    }
  }
  int row = blockIdx.x * 64 + (ty << 2);
  int col = blockIdx.y * 64 + (tx << 2);
  float4 bv = *(const float4*)(bias + col);
#pragma unroll
  for (int i = 0; i < 4; i++) {
    float4 c;
    c.x = acc[i][0] + bv.x;
    c.y = acc[i][1] + bv.y;
    c.z = acc[i][2] + bv.z;
    c.w = acc[i][3] + bv.w;
    if (GELU) {
      c.x = 0.5f * c.x * (1.0f + erff(c.x * 0.70710678118654752f));
      c.y = 0.5f * c.y * (1.0f + erff(c.y * 0.70710678118654752f));
      c.z = 0.5f * c.z * (1.0f + erff(c.z * 0.70710678118654752f));
      c.w = 0.5f * c.w * (1.0f + erff(c.w * 0.70710678118654752f));
    }
    if (RES) {
      float4 r4 = *(const float4*)(res + (size_t)(row + i) * N + col);
      c.x += r4.x; c.y += r4.y; c.z += r4.z; c.w += r4.w;
    }
    *(float4*)(C + (size_t)(row + i) * N + col) = c;
  }
}

// ---------------- MHA: one wave per (b,h,q-row), D=32, NK=1024 ----------------
__global__ __launch_bounds__(256) void attn_kernel(
    const float* __restrict__ qkv, float* __restrict__ o) {
  int lane = threadIdx.x & 63;
  int idx = (blockIdx.x << 2) + (threadIdx.x >> 6);  // (b*8+h)*1024 + qrow
  int qrow = idx & (NQR - 1);
  int bh = idx >> 10;
  int h = bh & 7, b = bh >> 3;
  const float* qp = qkv + (size_t)(b * NQR + qrow) * 768 + h * 32;
  float q[32];
#pragma unroll
  for (int i = 0; i < 8; i++) {
    float4 v = ((const float4*)qp)[i];
    q[4 * i] = v.x; q[4 * i + 1] = v.y; q[4 * i + 2] = v.z; q[4 * i + 3] = v.w;
  }
  const float* kb = qkv + (size_t)b * NQR * 768 + 256 + h * 32;
  const float* vb = kb + 256;
  float s[16];
  float mx = -1e30f;
#pragma unroll 4
  for (int jj = 0; jj < 16; jj++) {
    const float4* kp = (const float4*)(kb + (size_t)(jj * 64 + lane) * 768);
    float dot = 0.f;
#pragma unroll
    for (int i = 0; i < 8; i++) {
      float4 kv = kp[i];
      dot += q[4 * i] * kv.x + q[4 * i + 1] * kv.y + q[4 * i + 2] * kv.z + q[4 * i + 3] * kv.w;
    }
    s[jj] = dot * 0.17677669529663687f;  // 1/sqrt(32)
    mx = fmaxf(mx, s[jj]);
  }
#pragma unroll
  for (int off = 32; off; off >>= 1) mx = fmaxf(mx, __shfl_xor(mx, off));
  float sum = 0.f;
#pragma unroll
  for (int jj = 0; jj < 16; jj++) {
    s[jj] = __expf(s[jj] - mx);
    sum += s[jj];
  }
#pragma unroll
  for (int off = 32; off; off >>= 1) sum += __shfl_xor(sum, off);
  float inv = 1.0f / sum;
  float acc[32];
#pragma unroll
  for (int d = 0; d < 32; d++) acc[d] = 0.f;
#pragma unroll 4
  for (int jj = 0; jj < 16; jj++) {
    const float4* vp = (const float4*)(vb + (size_t)(jj * 64 + lane) * 768);
    float p = s[jj];
#pragma unroll
    for (int i = 0; i < 8; i++) {
      float4 vv = vp[i];
      acc[4 * i] += p * vv.x; acc[4 * i + 1] += p * vv.y;
      acc[4 * i + 2] += p * vv.z; acc[4 * i + 3] += p * vv.w;
    }
  }
#pragma unroll
  for (int off = 32; off; off >>= 1) {
#pragma unroll
    for (int d = 0; d < 32; d++) acc[d] += __shfl_xor(acc[d], off);
  }
  if (lane == 0) {
    float* op = o + (size_t)(b * NQR + qrow) * 256 + h * 32;
#pragma unroll
    for (int i = 0; i < 8; i++)
      ((float4*)op)[i] = make_float4(acc[4 * i] * inv, acc[4 * i + 1] * inv,
                                     acc[4 * i + 2] * inv, acc[4 * i + 3] * inv);
  }
}

// ---------------- reference points: sigmoid(q2 @ ref_w^T + ref_b), N=2 ----------------
__global__ __launch_bounds__(256) void ref_kernel(
    const float* __restrict__ q2, const float* __restrict__ rw,
    const float* __restrict__ rb, float* __restrict__ refo) {
  int lane = threadIdx.x & 63;
  int row = (blockIdx.x << 2) + (threadIdx.x >> 6);
  float4 x = ((const float4*)(q2 + (size_t)row * 256))[lane];
  float4 w0 = ((const float4*)rw)[lane];
  float4 w1 = ((const float4*)(rw + 256))[lane];
  float d0 = x.x * w0.x + x.y * w0.y + x.z * w0.z + x.w * w0.w;
  float d1 = x.x * w1.x + x.y * w1.y + x.z * w1.z + x.w * w1.w;
#pragma unroll
  for (int off = 32; off; off >>= 1) {
    d0 += __shfl_xor(d0, off);
    d1 += __shfl_xor(d1, off);
  }
  if (lane == 0) {
    refo[row * 2 + 0] = 1.0f / (1.0f + __expf(-(d0 + rb[0])));
    refo[row * 2 + 1] = 1.0f / (1.0f + __expf(-(d1 + rb[1])));
  }
}

// ---------------- msdeform sampling: block per (b,q), thread = (h,d) ----------------
__global__ __launch_bounds__(256) void msdeform_kernel(
    const float* __restrict__ value, const float* __restrict__ ref,
    const float* __restrict__ off, const float* __restrict__ aw_raw,
    float* __restrict__ out) {
  int bq = blockIdx.x;
  int b = bq >> 10;
  __shared__ float s_aw[192], s_lx[192], s_ly[192];
  __shared__ int s_x0[192], s_y0[192];
  int t = threadIdx.x;
  if (t < 192) {
    s_aw[t] = aw_raw[(size_t)bq * 192 + t];
    int l = (t % 24) >> 3;
    float dim = (l == 0) ? 128.f : ((l == 1) ? 64.f : 32.f);
    float rx = ref[bq * 2 + 0], ry = ref[bq * 2 + 1];
    float ox = off[(size_t)bq * 384 + t * 2 + 0];
    float oy = off[(size_t)bq * 384 + t * 2 + 1];
    float gx = rx * dim + ox - 0.5f;
    float gy = ry * dim + oy - 0.5f;
    float fx = floorf(gx), fy = floorf(gy);
    s_x0[t] = (int)fx;
    s_y0[t] = (int)fy;
    s_lx[t] = gx - fx;
    s_ly[t] = gy - fy;
  }
  __syncthreads();
  if (t < 8) {  // softmax over 24 per head
    float m = -1e30f;
#pragma unroll
    for (int i = 0; i < 24; i++) m = fmaxf(m, s_aw[t * 24 + i]);
    float sm = 0.f;
#pragma unroll
    for (int i = 0; i < 24; i++) {
      float e = __expf(s_aw[t * 24 + i] - m);
      s_aw[t * 24 + i] = e;
      sm += e;
    }
    float inv = 1.0f / sm;
#pragma unroll
    for (int i = 0; i < 24; i++) s_aw[t * 24 + i] *= inv;
  }
  __syncthreads();
  int h = t >> 5, d = t & 31;
  float acc = 0.f;
  const float* vb = value + (size_t)b * SROWS * 256 + h * 32 + d;
#pragma unroll
  for (int l = 0; l < 3; l++) {
    int start = (l == 0) ? 0 : ((l == 1) ? 16384 : 20480);
    int dim = (l == 0) ? 128 : ((l == 1) ? 64 : 32);
    const float* vl = vb + (size_t)start * 256;
#pragma unroll
    for (int p = 0; p < 8; p++) {
      int e = h * 24 + l * 8 + p;
      float w = s_aw[e];
      int x0 = s_x0[e], y0 = s_y0[e];
      float lx = s_lx[e], ly = s_ly[e];
      float v00 = 0.f, v01 = 0.f, v10 = 0.f, v11 = 0.f;
      bool xin0 = (x0 >= 0) & (x0 < dim);
      bool xin1 = (x0 + 1 >= 0) & (x0 + 1 < dim);
      bool yin0 = (y0 >= 0) & (y0 < dim);
      bool yin1 = (y0 + 1 >= 0) & (y0 + 1 < dim);
      if (yin0 && xin0) v00 = vl[(size_t)(y0 * dim + x0) * 256];
      if (yin0 && xin1) v01 = vl[(size_t)(y0 * dim + x0 + 1) * 256];
      if (yin1 && xin0) v10 = vl[(size_t)((y0 + 1) * dim + x0) * 256];
      if (yin1 && xin1) v11 = vl[(size_t)((y0 + 1) * dim + x0 + 1) * 256];
      acc += w * (v00 * (1.f - lx) * (1.f - ly) + v01 * lx * (1.f - ly) +
                  v10 * (1.f - lx) * ly + v11 * lx * ly);
    }
  }
  out[(size_t)bq * 256 + t] = acc;
}

extern "C" void kernel_launch(void* const* d_in, const int* in_sizes, int n_in,
                              void* d_out, int out_size, void* d_ws, size_t ws_size,
                              hipStream_t stream) {
  const float* tgt = (const float*)d_in[0];
  const float* memory = (const float*)d_in[1];
  const float* n1_w = (const float*)d_in[2];
  const float* n1_b = (const float*)d_in[3];
  const float* attn_in_w = (const float*)d_in[4];
  const float* attn_in_b = (const float*)d_in[5];
  const float* attn_out_w = (const float*)d_in[6];
  const float* attn_out_b = (const float*)d_in[7];
  const float* n2_w = (const float*)d_in[8];
  const float* n2_b = (const float*)d_in[9];
  const float* ref_w = (const float*)d_in[10];
  const float* ref_b = (const float*)d_in[11];
  const float* so_w = (const float*)d_in[12];
  const float* so_b = (const float*)d_in[13];
  const float* aw_w = (const float*)d_in[14];
  const float* aw_b = (const float*)d_in[15];
  const float* vp_w = (const float*)d_in[16];
  const float* vp_b = (const float*)d_in[17];
  const float* op_w = (const float*)d_in[18];
  const float* op_b = (const float*)d_in[19];
  const float* n3_w = (const float*)d_in[20];
  const float* n3_b = (const float*)d_in[21];
  const float* l1_w = (const float*)d_in[22];
  const float* l1_b = (const float*)d_in[23];
  const float* l2_w = (const float*)d_in[24];
  const float* l2_b = (const float*)d_in[25];
  float* out = (float*)d_out;

  float* ws = (float*)d_ws;
  float* q_buf = ws;                     // 2,097,152  (q1/q2/q3)
  float* bufB = q_buf + 2097152;         // 8,388,608  (qkv / ff1)
  float* bufC = bufB + 8388608;          // 2,097,152  (mha_o / sampled)
  float* ref_buf = bufC + 2097152;       // 16,384
  float* off_buf = ref_buf + 16384;      // 3,145,728
  float* aw_buf = off_buf + 3145728;     // 1,572,864
  float* val_buf = aw_buf + 1572864;     // 44,040,192
  // total ~245.4 MB

  const int NR = 8192;  // B*NQ rows

  // ---- self-attention block ----
  ln_kernel<<<NR / 4, 256, 0, stream>>>(tgt, n1_w, n1_b, q_buf);
  gemm_kernel<false, false><<<dim3(NR / 64, 768 / 64), 256, 0, stream>>>(
      q_buf, attn_in_w, attn_in_b, nullptr, bufB, NR, 768, 256);
  attn_kernel<<<(8 * 8 * NQR) / 4, 256, 0, stream>>>(bufB, bufC);
  gemm_kernel<false, true><<<dim3(NR / 64, 256 / 64), 256, 0, stream>>>(
      bufC, attn_out_w, attn_out_b, tgt, out, NR, 256, 256);

  // ---- deformable cross-attention block ----
  ln_kernel<<<NR / 4, 256, 0, stream>>>(out, n2_w, n2_b, q_buf);
  gemm_kernel<false, false><<<dim3(8 * SROWS / 64, 256 / 64), 256, 0, stream>>>(
      memory, vp_w, vp_b, nullptr, val_buf, 8 * SROWS, 256, 256);
  ref_kernel<<<NR / 4, 256, 0, stream>>>(q_buf, ref_w, ref_b, ref_buf);
  gemm_kernel<false, false><<<dim3(NR / 64, 384 / 64), 256, 0, stream>>>(
      q_buf, so_w, so_b, nullptr, off_buf, NR, 384, 256);
  gemm_kernel<false, false><<<dim3(NR / 64, 192 / 64), 256, 0, stream>>>(
      q_buf, aw_w, aw_b, nullptr, aw_buf, NR, 192, 256);
  msdeform_kernel<<<NR, 256, 0, stream>>>(val_buf, ref_buf, off_buf, aw_buf, bufC);
  gemm_kernel<false, true><<<dim3(NR / 64, 256 / 64), 256, 0, stream>>>(
      bufC, op_w, op_b, out, out, NR, 256, 256);

  // ---- FFN block ----
  ln_kernel<<<NR / 4, 256, 0, stream>>>(out, n3_w, n3_b, q_buf);
  gemm_kernel<true, false><<<dim3(NR / 64, 1024 / 64), 256, 0, stream>>>(
      q_buf, l1_w, l1_b, nullptr, bufB, NR, 1024, 256);
  gemm_kernel<false, true><<<dim3(NR / 64, 256 / 64), 256, 0, stream>>>(
      bufB, l2_w, l2_b, out, out, NR, 256, 1024);
}

// Round 3
// 1212.281 us; speedup vs baseline: 2.3351x; 2.3351x over previous
//
#include <hip/hip_runtime.h>
#include <math.h>

#define NQR 1024
#define CDIM 256
#define SROWS 21504
#define ATTN_SCALE 0.17677669529663687f

// ---------------- LayerNorm: one wave per 256-wide row ----------------
__global__ __launch_bounds__(256) void ln_kernel(
    const float* __restrict__ x, const float* __restrict__ w,
    const float* __restrict__ b, float* __restrict__ y) {
  int lane = threadIdx.x & 63;
  int row = (blockIdx.x << 2) + (threadIdx.x >> 6);
  float4 v = ((const float4*)(x + (size_t)row * CDIM))[lane];
  float s = v.x + v.y + v.z + v.w;
  float ss = v.x * v.x + v.y * v.y + v.z * v.z + v.w * v.w;
#pragma unroll
  for (int off = 32; off; off >>= 1) {
    s += __shfl_xor(s, off);
    ss += __shfl_xor(ss, off);
  }
  float m = s * (1.0f / 256.0f);
  float var = ss * (1.0f / 256.0f) - m * m;
  float r = rsqrtf(var + 1e-5f);
  float4 wv = ((const float4*)w)[lane];
  float4 bv = ((const float4*)b)[lane];
  float4 o;
  o.x = (v.x - m) * r * wv.x + bv.x;
  o.y = (v.y - m) * r * wv.y + bv.y;
  o.z = (v.z - m) * r * wv.z + bv.z;
  o.w = (v.w - m) * r * wv.w + bv.w;
  ((float4*)(y + (size_t)row * CDIM))[lane] = o;
}

// ---------------- Generic fp32 GEMM: C[M,N] = A[M,K] @ W[N,K]^T + bias (+res, +gelu) ----
template <bool GELU, bool RES>
__global__ __launch_bounds__(256) void gemm_kernel(
    const float* __restrict__ A, const float* __restrict__ W,
    const float* __restrict__ bias, const float* __restrict__ res,
    float* __restrict__ C, int M, int N, int K) {
  __shared__ float As[16][64];
  __shared__ float Bs[16][64];
  int t = threadIdx.x;
  int tx = t & 15, ty = t >> 4;
  int arow = t >> 2;
  int acol = (t & 3) << 2;
  const float* Ap = A + (size_t)(blockIdx.x * 64 + arow) * K + acol;
  const float* Wp = W + (size_t)(blockIdx.y * 64 + arow) * K + acol;
  float acc[4][4] = {};
  for (int k0 = 0; k0 < K; k0 += 16) {
    float4 av = *(const float4*)(Ap + k0);
    float4 wv = *(const float4*)(Wp + k0);
    __syncthreads();
    As[acol + 0][arow] = av.x;
    As[acol + 1][arow] = av.y;
    As[acol + 2][arow] = av.z;
    As[acol + 3][arow] = av.w;
    Bs[acol + 0][arow] = wv.x;
    Bs[acol + 1][arow] = wv.y;
    Bs[acol + 2][arow] = wv.z;
    Bs[acol + 3][arow] = wv.w;
    __syncthreads();
#pragma unroll
    for (int kk = 0; kk < 16; kk++) {
      float4 a = *(const float4*)(&As[kk][ty << 2]);
      float4 bb = *(const float4*)(&Bs[kk][tx << 2]);
      acc[0][0] += a.x * bb.x; acc[0][1] += a.x * bb.y; acc[0][2] += a.x * bb.z; acc[0][3] += a.x * bb.w;
      acc[1][0] += a.y * bb.x; acc[1][1] += a.y * bb.y; acc[1][2] += a.y * bb.z; acc[1][3] += a.y * bb.w;
      acc[2][0] += a.z * bb.x; acc[2][1] += a.z * bb.y; acc[2][2] += a.z * bb.z; acc[2][3] += a.z * bb.w;
      acc[3][0] += a.w * bb.x; acc[3][1] += a.w * bb.y; acc[3][2] += a.w * bb.z; acc[3][3] += a.w * bb.w;
    }
  }
  int row = blockIdx.x * 64 + (ty << 2);
  int col = blockIdx.y * 64 + (tx << 2);
  float4 bv = *(const float4*)(bias + col);
#pragma unroll
  for (int i = 0; i < 4; i++) {
    float4 c;
    c.x = acc[i][0] + bv.x;
    c.y = acc[i][1] + bv.y;
    c.z = acc[i][2] + bv.z;
    c.w = acc[i][3] + bv.w;
    if (GELU) {
      c.x = 0.5f * c.x * (1.0f + erff(c.x * 0.70710678118654752f));
      c.y = 0.5f * c.y * (1.0f + erff(c.y * 0.70710678118654752f));
      c.z = 0.5f * c.z * (1.0f + erff(c.z * 0.70710678118654752f));
      c.w = 0.5f * c.w * (1.0f + erff(c.w * 0.70710678118654752f));
    }
    if (RES) {
      float4 r4 = *(const float4*)(res + (size_t)(row + i) * N + col);
      c.x += r4.x; c.y += r4.y; c.z += r4.z; c.w += r4.w;
    }
    *(float4*)(C + (size_t)(row + i) * N + col) = c;
  }
}

// ---------------- Flash-style tiled MHA ----------------
// Block = (b, h, q-tile of 64 rows). 256 threads as 16x16 grid, 4x4 S-microtile,
// online softmax; K/V staged in LDS per 64-row k-tile, Q/K transposed in LDS.
__global__ __launch_bounds__(256) void attn_tiled(
    const float* __restrict__ qkv, float* __restrict__ o) {
  __shared__ float QsT[32][68];
  __shared__ float KsT[32][68];
  __shared__ float Vs[64][36];
  __shared__ float Ps[64][68];
  int qt = blockIdx.x;          // 16 q-tiles
  int bh = blockIdx.y;          // 64 (b,h)
  int b = bh >> 3, h = bh & 7;
  int t = threadIdx.x;
  int tx = t & 15, ty = t >> 4;
  int lr = t >> 2;              // loader row 0..63
  int lc = (t & 3) << 2;        // loader col 0,4,8,12 (+16 for second half)

  // load Q tile transposed, pre-scaled by 1/sqrt(D)
  {
    const float* qp = qkv + ((size_t)(b * NQR + qt * 64 + lr)) * 768 + h * 32;
    float4 a = *(const float4*)(qp + lc);
    float4 b4 = *(const float4*)(qp + lc + 16);
    QsT[lc + 0][lr] = a.x * ATTN_SCALE;
    QsT[lc + 1][lr] = a.y * ATTN_SCALE;
    QsT[lc + 2][lr] = a.z * ATTN_SCALE;
    QsT[lc + 3][lr] = a.w * ATTN_SCALE;
    QsT[lc + 16][lr] = b4.x * ATTN_SCALE;
    QsT[lc + 17][lr] = b4.y * ATTN_SCALE;
    QsT[lc + 18][lr] = b4.z * ATTN_SCALE;
    QsT[lc + 19][lr] = b4.w * ATTN_SCALE;
  }
  float m[4] = {-1e30f, -1e30f, -1e30f, -1e30f};
  float l[4] = {0.f, 0.f, 0.f, 0.f};
  float acc[4][2] = {};

  for (int kt = 0; kt < 16; kt++) {
    // issue next K/V global loads before waiting on previous PV consumers
    const float* kp = qkv + ((size_t)(b * NQR + kt * 64 + lr)) * 768 + 256 + h * 32;
    float4 k0 = *(const float4*)(kp + lc);
    float4 k1 = *(const float4*)(kp + lc + 16);
    const float* vp = kp + 256;
    float4 w0 = *(const float4*)(vp + lc);
    float4 w1 = *(const float4*)(vp + lc + 16);
    __syncthreads();
    KsT[lc + 0][lr] = k0.x;
    KsT[lc + 1][lr] = k0.y;
    KsT[lc + 2][lr] = k0.z;
    KsT[lc + 3][lr] = k0.w;
    KsT[lc + 16][lr] = k1.x;
    KsT[lc + 17][lr] = k1.y;
    KsT[lc + 18][lr] = k1.z;
    KsT[lc + 19][lr] = k1.w;
    *(float4*)&Vs[lr][lc] = w0;
    *(float4*)&Vs[lr][lc + 16] = w1;
    __syncthreads();
    // S = Q·K^T, 4x4 per thread: rows 4ty+r, cols 4tx+c
    float s[4][4] = {};
#pragma unroll
    for (int d = 0; d < 32; d++) {
      float4 a = *(const float4*)&QsT[d][ty << 2];
      float4 k = *(const float4*)&KsT[d][tx << 2];
      s[0][0] += a.x * k.x; s[0][1] += a.x * k.y; s[0][2] += a.x * k.z; s[0][3] += a.x * k.w;
      s[1][0] += a.y * k.x; s[1][1] += a.y * k.y; s[1][2] += a.y * k.z; s[1][3] += a.y * k.w;
      s[2][0] += a.z * k.x; s[2][1] += a.z * k.y; s[2][2] += a.z * k.z; s[2][3] += a.z * k.w;
      s[3][0] += a.w * k.x; s[3][1] += a.w * k.y; s[3][2] += a.w * k.z; s[3][3] += a.w * k.w;
    }
    // online softmax per row (reduce across the 16-lane tx group)
#pragma unroll
    for (int r = 0; r < 4; r++) {
      float mt = fmaxf(fmaxf(s[r][0], s[r][1]), fmaxf(s[r][2], s[r][3]));
      mt = fmaxf(mt, __shfl_xor(mt, 1));
      mt = fmaxf(mt, __shfl_xor(mt, 2));
      mt = fmaxf(mt, __shfl_xor(mt, 4));
      mt = fmaxf(mt, __shfl_xor(mt, 8));
      float mn = fmaxf(m[r], mt);
      float sc = __expf(m[r] - mn);
      m[r] = mn;
      float rs = 0.f;
#pragma unroll
      for (int c = 0; c < 4; c++) {
        s[r][c] = __expf(s[r][c] - mn);
        rs += s[r][c];
      }
      rs += __shfl_xor(rs, 1);
      rs += __shfl_xor(rs, 2);
      rs += __shfl_xor(rs, 4);
      rs += __shfl_xor(rs, 8);
      l[r] = l[r] * sc + rs;
      acc[r][0] *= sc;
      acc[r][1] *= sc;
      *(float4*)&Ps[(ty << 2) + r][tx << 2] = make_float4(s[r][0], s[r][1], s[r][2], s[r][3]);
    }
    __syncthreads();
    // O += P·V : O rows 4ty+r, d cols 2tx+{0,1}
#pragma unroll 4
    for (int k4 = 0; k4 < 16; k4++) {
      float pv[4][4];
#pragma unroll
      for (int r = 0; r < 4; r++) {
        float4 p4 = *(const float4*)&Ps[(ty << 2) + r][k4 << 2];
        pv[r][0] = p4.x; pv[r][1] = p4.y; pv[r][2] = p4.z; pv[r][3] = p4.w;
      }
#pragma unroll
      for (int j = 0; j < 4; j++) {
        float2 v = *(const float2*)&Vs[(k4 << 2) + j][tx << 1];
#pragma unroll
        for (int r = 0; r < 4; r++) {
          acc[r][0] += pv[r][j] * v.x;
          acc[r][1] += pv[r][j] * v.y;
        }
      }
    }
  }
  // epilogue: divide by l, store
  float* op = o + ((size_t)(b * NQR + qt * 64)) * 256 + h * 32;
#pragma unroll
  for (int r = 0; r < 4; r++) {
    float inv = 1.0f / l[r];
    *(float2*)(op + (size_t)((ty << 2) + r) * 256 + (tx << 1)) =
        make_float2(acc[r][0] * inv, acc[r][1] * inv);
  }
}

// ---------------- reference points: sigmoid(q2 @ ref_w^T + ref_b), N=2 ----------------
__global__ __launch_bounds__(256) void ref_kernel(
    const float* __restrict__ q2, const float* __restrict__ rw,
    const float* __restrict__ rb, float* __restrict__ refo) {
  int lane = threadIdx.x & 63;
  int row = (blockIdx.x << 2) + (threadIdx.x >> 6);
  float4 x = ((const float4*)(q2 + (size_t)row * 256))[lane];
  float4 w0 = ((const float4*)rw)[lane];
  float4 w1 = ((const float4*)(rw + 256))[lane];
  float d0 = x.x * w0.x + x.y * w0.y + x.z * w0.z + x.w * w0.w;
  float d1 = x.x * w1.x + x.y * w1.y + x.z * w1.z + x.w * w1.w;
#pragma unroll
  for (int off = 32; off; off >>= 1) {
    d0 += __shfl_xor(d0, off);
    d1 += __shfl_xor(d1, off);
  }
  if (lane == 0) {
    refo[row * 2 + 0] = 1.0f / (1.0f + __expf(-(d0 + rb[0])));
    refo[row * 2 + 1] = 1.0f / (1.0f + __expf(-(d1 + rb[1])));
  }
}

// ---------------- msdeform sampling: block per (b,q), thread = (h,d) ----------------
__global__ __launch_bounds__(256) void msdeform_kernel(
    const float* __restrict__ value, const float* __restrict__ ref,
    const float* __restrict__ off, const float* __restrict__ aw_raw,
    float* __restrict__ out) {
  int bq = blockIdx.x;
  int b = bq >> 10;
  __shared__ float s_aw[192], s_lx[192], s_ly[192];
  __shared__ int s_x0[192], s_y0[192];
  int t = threadIdx.x;
  if (t < 192) {
    s_aw[t] = aw_raw[(size_t)bq * 192 + t];
    int l = (t % 24) >> 3;
    float dim = (l == 0) ? 128.f : ((l == 1) ? 64.f : 32.f);
    float rx = ref[bq * 2 + 0], ry = ref[bq * 2 + 1];
    float ox = off[(size_t)bq * 384 + t * 2 + 0];
    float oy = off[(size_t)bq * 384 + t * 2 + 1];
    float gx = rx * dim + ox - 0.5f;
    float gy = ry * dim + oy - 0.5f;
    float fx = floorf(gx), fy = floorf(gy);
    s_x0[t] = (int)fx;
    s_y0[t] = (int)fy;
    s_lx[t] = gx - fx;
    s_ly[t] = gy - fy;
  }
  __syncthreads();
  if (t < 8) {
    float m = -1e30f;
#pragma unroll
    for (int i = 0; i < 24; i++) m = fmaxf(m, s_aw[t * 24 + i]);
    float sm = 0.f;
#pragma unroll
    for (int i = 0; i < 24; i++) {
      float e = __expf(s_aw[t * 24 + i] - m);
      s_aw[t * 24 + i] = e;
      sm += e;
    }
    float inv = 1.0f / sm;
#pragma unroll
    for (int i = 0; i < 24; i++) s_aw[t * 24 + i] *= inv;
  }
  __syncthreads();
  int h = t >> 5, d = t & 31;
  float acc = 0.f;
  const float* vb = value + (size_t)b * SROWS * 256 + h * 32 + d;
#pragma unroll
  for (int l = 0; l < 3; l++) {
    int start = (l == 0) ? 0 : ((l == 1) ? 16384 : 20480);
    int dim = (l == 0) ? 128 : ((l == 1) ? 64 : 32);
    const float* vl = vb + (size_t)start * 256;
#pragma unroll
    for (int p = 0; p < 8; p++) {
      int e = h * 24 + l * 8 + p;
      float w = s_aw[e];
      int x0 = s_x0[e], y0 = s_y0[e];
      float lx = s_lx[e], ly = s_ly[e];
      float v00 = 0.f, v01 = 0.f, v10 = 0.f, v11 = 0.f;
      bool xin0 = (x0 >= 0) & (x0 < dim);
      bool xin1 = (x0 + 1 >= 0) & (x0 + 1 < dim);
      bool yin0 = (y0 >= 0) & (y0 < dim);
      bool yin1 = (y0 + 1 >= 0) & (y0 + 1 < dim);
      if (yin0 && xin0) v00 = vl[(size_t)(y0 * dim + x0) * 256];
      if (yin0 && xin1) v01 = vl[(size_t)(y0 * dim + x0 + 1) * 256];
      if (yin1 && xin0) v10 = vl[(size_t)((y0 + 1) * dim + x0) * 256];
      if (yin1 && xin1) v11 = vl[(size_t)((y0 + 1) * dim + x0 + 1) * 256];
      acc += w * (v00 * (1.f - lx) * (1.f - ly) + v01 * lx * (1.f - ly) +
                  v10 * (1.f - lx) * ly + v11 * lx * ly);
    }
  }
  out[(size_t)bq * 256 + t] = acc;
}

extern "C" void kernel_launch(void* const* d_in, const int* in_sizes, int n_in,
                              void* d_out, int out_size, void* d_ws, size_t ws_size,
                              hipStream_t stream) {
  const float* tgt = (const float*)d_in[0];
  const float* memory = (const float*)d_in[1];
  const float* n1_w = (const float*)d_in[2];
  const float* n1_b = (const float*)d_in[3];
  const float* attn_in_w = (const float*)d_in[4];
  const float* attn_in_b = (const float*)d_in[5];
  const float* attn_out_w = (const float*)d_in[6];
  const float* attn_out_b = (const float*)d_in[7];
  const float* n2_w = (const float*)d_in[8];
  const float* n2_b = (const float*)d_in[9];
  const float* ref_w = (const float*)d_in[10];
  const float* ref_b = (const float*)d_in[11];
  const float* so_w = (const float*)d_in[12];
  const float* so_b = (const float*)d_in[13];
  const float* aw_w = (const float*)d_in[14];
  const float* aw_b = (const float*)d_in[15];
  const float* vp_w = (const float*)d_in[16];
  const float* vp_b = (const float*)d_in[17];
  const float* op_w = (const float*)d_in[18];
  const float* op_b = (const float*)d_in[19];
  const float* n3_w = (const float*)d_in[20];
  const float* n3_b = (const float*)d_in[21];
  const float* l1_w = (const float*)d_in[22];
  const float* l1_b = (const float*)d_in[23];
  const float* l2_w = (const float*)d_in[24];
  const float* l2_b = (const float*)d_in[25];
  float* out = (float*)d_out;

  float* ws = (float*)d_ws;
  float* q_buf = ws;                     // 2,097,152  (q1/q2/q3)
  float* bufB = q_buf + 2097152;         // 8,388,608  (qkv / ff1)
  float* bufC = bufB + 8388608;          // 2,097,152  (mha_o / sampled)
  float* ref_buf = bufC + 2097152;       // 16,384
  float* off_buf = ref_buf + 16384;      // 3,145,728
  float* aw_buf = off_buf + 3145728;     // 1,572,864
  float* val_buf = aw_buf + 1572864;     // 44,040,192
  // total ~245.4 MB

  const int NR = 8192;  // B*NQ rows

  // ---- self-attention block ----
  ln_kernel<<<NR / 4, 256, 0, stream>>>(tgt, n1_w, n1_b, q_buf);
  gemm_kernel<false, false><<<dim3(NR / 64, 768 / 64), 256, 0, stream>>>(
      q_buf, attn_in_w, attn_in_b, nullptr, bufB, NR, 768, 256);
  attn_tiled<<<dim3(16, 64), 256, 0, stream>>>(bufB, bufC);
  gemm_kernel<false, true><<<dim3(NR / 64, 256 / 64), 256, 0, stream>>>(
      bufC, attn_out_w, attn_out_b, tgt, out, NR, 256, 256);

  // ---- deformable cross-attention block ----
  ln_kernel<<<NR / 4, 256, 0, stream>>>(out, n2_w, n2_b, q_buf);
  gemm_kernel<false, false><<<dim3(8 * SROWS / 64, 256 / 64), 256, 0, stream>>>(
      memory, vp_w, vp_b, nullptr, val_buf, 8 * SROWS, 256, 256);
  ref_kernel<<<NR / 4, 256, 0, stream>>>(q_buf, ref_w, ref_b, ref_buf);
  gemm_kernel<false, false><<<dim3(NR / 64, 384 / 64), 256, 0, stream>>>(
      q_buf, so_w, so_b, nullptr, off_buf, NR, 384, 256);
  gemm_kernel<false, false><<<dim3(NR / 64, 192 / 64), 256, 0, stream>>>(
      q_buf, aw_w, aw_b, nullptr, aw_buf, NR, 192, 256);
  msdeform_kernel<<<NR, 256, 0, stream>>>(val_buf, ref_buf, off_buf, aw_buf, bufC);
  gemm_kernel<false, true><<<dim3(NR / 64, 256 / 64), 256, 0, stream>>>(
      bufC, op_w, op_b, out, out, NR, 256, 256);

  // ---- FFN block ----
  ln_kernel<<<NR / 4, 256, 0, stream>>>(out, n3_w, n3_b, q_buf);
  gemm_kernel<true, false><<<dim3(NR / 64, 1024 / 64), 256, 0, stream>>>(
      q_buf, l1_w, l1_b, nullptr, bufB, NR, 1024, 256);
  gemm_kernel<false, true><<<dim3(NR / 64, 256 / 64), 256, 0, stream>>>(
      bufB, l2_w, l2_b, out, out, NR, 256, 1024);
}

// Round 4
// 1022.686 us; speedup vs baseline: 2.7680x; 1.1854x over previous
//
#include <hip/hip_runtime.h>
#include <math.h>

#define NQR 1024
#define CDIM 256
#define SROWS 21504
#define ATTN_SCALE 0.17677669529663687f

typedef __attribute__((ext_vector_type(8))) short bf16x8;
typedef __attribute__((ext_vector_type(4))) float f32x4;

__device__ __forceinline__ ushort f2b(float x) {  // fp32 -> bf16 bits, RNE
  unsigned u = __float_as_uint(x);
  u += 0x7FFFu + ((u >> 16) & 1u);
  return (ushort)(u >> 16);
}
__device__ __forceinline__ float b2f(ushort b) {
  return __uint_as_float(((unsigned)b) << 16);
}

// ---------------- fp32 -> bf16 elementwise convert (n multiple of 2048) ----------------
__global__ __launch_bounds__(256) void f2bf_kernel(
    const float* __restrict__ x, ushort* __restrict__ y) {
  int i = blockIdx.x * 256 + threadIdx.x;  // each thread: 8 elements
  float4 v0 = ((const float4*)x)[i * 2];
  float4 v1 = ((const float4*)x)[i * 2 + 1];
  ushort4 o0, o1;
  o0.x = f2b(v0.x); o0.y = f2b(v0.y); o0.z = f2b(v0.z); o0.w = f2b(v0.w);
  o1.x = f2b(v1.x); o1.y = f2b(v1.y); o1.z = f2b(v1.z); o1.w = f2b(v1.w);
  ((ushort4*)y)[i * 2] = o0;
  ((ushort4*)y)[i * 2 + 1] = o1;
}

// ---------------- LayerNorm: one wave per 256-wide row, bf16 out ----------------
__global__ __launch_bounds__(256) void ln_kernel(
    const float* __restrict__ x, const float* __restrict__ w,
    const float* __restrict__ b, ushort* __restrict__ y) {
  int lane = threadIdx.x & 63;
  int row = (blockIdx.x << 2) + (threadIdx.x >> 6);
  float4 v = ((const float4*)(x + (size_t)row * CDIM))[lane];
  float s = v.x + v.y + v.z + v.w;
  float ss = v.x * v.x + v.y * v.y + v.z * v.z + v.w * v.w;
#pragma unroll
  for (int off = 32; off; off >>= 1) {
    s += __shfl_xor(s, off);
    ss += __shfl_xor(ss, off);
  }
  float m = s * (1.0f / 256.0f);
  float var = ss * (1.0f / 256.0f) - m * m;
  float r = rsqrtf(var + 1e-5f);
  float4 wv = ((const float4*)w)[lane];
  float4 bv = ((const float4*)b)[lane];
  ushort4 o;
  o.x = f2b((v.x - m) * r * wv.x + bv.x);
  o.y = f2b((v.y - m) * r * wv.y + bv.y);
  o.z = f2b((v.z - m) * r * wv.z + bv.z);
  o.w = f2b((v.w - m) * r * wv.w + bv.w);
  ((ushort4*)(y + (size_t)row * CDIM))[lane] = o;
}

// ---------------- bf16 MFMA GEMM: C[M,N] = A[M,K] @ W[N,K]^T + bias (+gelu, +res) ----
// BM=128, BN=64, BK=64. 256 threads = 4 waves (2x2), wave tile 64x32, frags 4x2.
// LDS rows padded to 72 shorts (144 B): bank-start stride 4 -> 2-way (free).
template <bool GELU, bool RES, bool OUTBF>
__global__ __launch_bounds__(256) void gemm_bf16(
    const short* __restrict__ A, const short* __restrict__ W,
    const float* __restrict__ bias, const float* __restrict__ res,
    void* __restrict__ Cout, int M, int N, int K) {
  __shared__ short As[128 * 72];
  __shared__ short Bs[64 * 72];
  int t = threadIdx.x;
  int l = t & 63;
  int wave = t >> 6;
  int wm = wave >> 1, wn = wave & 1;
  int lrow = t >> 3;        // 0..31
  int lcol = (t & 7) << 3;  // 0..56
  size_t m0 = (size_t)blockIdx.x * 128;
  int n0 = blockIdx.y * 64;
  const short* Ag = A + (m0 + lrow) * K + lcol;
  const short* Wg = W + (size_t)(n0 + lrow) * K + lcol;
  f32x4 acc[4][2] = {};
  int fr = l & 15, fq = l >> 4;
  for (int k0 = 0; k0 < K; k0 += 64) {
    uint4 a0 = *(const uint4*)(Ag + k0);
    uint4 a1 = *(const uint4*)(Ag + (size_t)32 * K + k0);
    uint4 a2 = *(const uint4*)(Ag + (size_t)64 * K + k0);
    uint4 a3 = *(const uint4*)(Ag + (size_t)96 * K + k0);
    uint4 b0 = *(const uint4*)(Wg + k0);
    uint4 b1 = *(const uint4*)(Wg + (size_t)32 * K + k0);
    __syncthreads();
    *(uint4*)&As[lrow * 72 + lcol] = a0;
    *(uint4*)&As[(lrow + 32) * 72 + lcol] = a1;
    *(uint4*)&As[(lrow + 64) * 72 + lcol] = a2;
    *(uint4*)&As[(lrow + 96) * 72 + lcol] = a3;
    *(uint4*)&Bs[lrow * 72 + lcol] = b0;
    *(uint4*)&Bs[(lrow + 32) * 72 + lcol] = b1;
    __syncthreads();
#pragma unroll
    for (int kk = 0; kk < 2; kk++) {
      int kb = kk * 32 + fq * 8;
      bf16x8 af[4], bfr[2];
#pragma unroll
      for (int mi = 0; mi < 4; mi++)
        af[mi] = *(const bf16x8*)&As[(wm * 64 + mi * 16 + fr) * 72 + kb];
#pragma unroll
      for (int ni = 0; ni < 2; ni++)
        bfr[ni] = *(const bf16x8*)&Bs[(wn * 32 + ni * 16 + fr) * 72 + kb];
#pragma unroll
      for (int mi = 0; mi < 4; mi++)
#pragma unroll
        for (int ni = 0; ni < 2; ni++)
          acc[mi][ni] = __builtin_amdgcn_mfma_f32_16x16x32_bf16(
              af[mi], bfr[ni], acc[mi][ni], 0, 0, 0);
    }
  }
  // epilogue: C[m0 + wm*64 + mi*16 + fq*4 + j][n0 + wn*32 + ni*16 + fr]
#pragma unroll
  for (int ni = 0; ni < 2; ni++) {
    int gcol = n0 + wn * 32 + ni * 16 + fr;
    float bv = bias[gcol];
#pragma unroll
    for (int mi = 0; mi < 4; mi++) {
#pragma unroll
      for (int j = 0; j < 4; j++) {
        size_t grow = m0 + wm * 64 + mi * 16 + fq * 4 + j;
        float v = acc[mi][ni][j] + bv;
        if (GELU) v = 0.5f * v * (1.0f + erff(v * 0.70710678118654752f));
        if (RES) v += res[grow * N + gcol];
        if (OUTBF)
          ((ushort*)Cout)[grow * N + gcol] = f2b(v);
        else
          ((float*)Cout)[grow * N + gcol] = v;
      }
    }
  }
}

// ---------------- Flash-style tiled MHA (fp32 in, bf16 out) ----------------
__global__ __launch_bounds__(256) void attn_tiled(
    const float* __restrict__ qkv, ushort* __restrict__ o) {
  __shared__ float QsT[32][68];
  __shared__ float KsT[32][68];
  __shared__ float Vs[64][36];
  __shared__ float Ps[64][68];
  int qt = blockIdx.x;
  int bh = blockIdx.y;
  int b = bh >> 3, h = bh & 7;
  int t = threadIdx.x;
  int tx = t & 15, ty = t >> 4;
  int lr = t >> 2;
  int lc = (t & 3) << 2;

  {
    const float* qp = qkv + ((size_t)(b * NQR + qt * 64 + lr)) * 768 + h * 32;
    float4 a = *(const float4*)(qp + lc);
    float4 b4 = *(const float4*)(qp + lc + 16);
    QsT[lc + 0][lr] = a.x * ATTN_SCALE;
    QsT[lc + 1][lr] = a.y * ATTN_SCALE;
    QsT[lc + 2][lr] = a.z * ATTN_SCALE;
    QsT[lc + 3][lr] = a.w * ATTN_SCALE;
    QsT[lc + 16][lr] = b4.x * ATTN_SCALE;
    QsT[lc + 17][lr] = b4.y * ATTN_SCALE;
    QsT[lc + 18][lr] = b4.z * ATTN_SCALE;
    QsT[lc + 19][lr] = b4.w * ATTN_SCALE;
  }
  float m[4] = {-1e30f, -1e30f, -1e30f, -1e30f};
  float lsum[4] = {0.f, 0.f, 0.f, 0.f};
  float acc[4][2] = {};

  for (int kt = 0; kt < 16; kt++) {
    const float* kp = qkv + ((size_t)(b * NQR + kt * 64 + lr)) * 768 + 256 + h * 32;
    float4 k0 = *(const float4*)(kp + lc);
    float4 k1 = *(const float4*)(kp + lc + 16);
    const float* vp = kp + 256;
    float4 w0 = *(const float4*)(vp + lc);
    float4 w1 = *(const float4*)(vp + lc + 16);
    __syncthreads();
    KsT[lc + 0][lr] = k0.x;
    KsT[lc + 1][lr] = k0.y;
    KsT[lc + 2][lr] = k0.z;
    KsT[lc + 3][lr] = k0.w;
    KsT[lc + 16][lr] = k1.x;
    KsT[lc + 17][lr] = k1.y;
    KsT[lc + 18][lr] = k1.z;
    KsT[lc + 19][lr] = k1.w;
    *(float4*)&Vs[lr][lc] = w0;
    *(float4*)&Vs[lr][lc + 16] = w1;
    __syncthreads();
    float s[4][4] = {};
#pragma unroll
    for (int d = 0; d < 32; d++) {
      float4 a = *(const float4*)&QsT[d][ty << 2];
      float4 k = *(const float4*)&KsT[d][tx << 2];
      s[0][0] += a.x * k.x; s[0][1] += a.x * k.y; s[0][2] += a.x * k.z; s[0][3] += a.x * k.w;
      s[1][0] += a.y * k.x; s[1][1] += a.y * k.y; s[1][2] += a.y * k.z; s[1][3] += a.y * k.w;
      s[2][0] += a.z * k.x; s[2][1] += a.z * k.y; s[2][2] += a.z * k.z; s[2][3] += a.z * k.w;
      s[3][0] += a.w * k.x; s[3][1] += a.w * k.y; s[3][2] += a.w * k.z; s[3][3] += a.w * k.w;
    }
#pragma unroll
    for (int r = 0; r < 4; r++) {
      float mt = fmaxf(fmaxf(s[r][0], s[r][1]), fmaxf(s[r][2], s[r][3]));
      mt = fmaxf(mt, __shfl_xor(mt, 1));
      mt = fmaxf(mt, __shfl_xor(mt, 2));
      mt = fmaxf(mt, __shfl_xor(mt, 4));
      mt = fmaxf(mt, __shfl_xor(mt, 8));
      float mn = fmaxf(m[r], mt);
      float sc = __expf(m[r] - mn);
      m[r] = mn;
      float rs = 0.f;
#pragma unroll
      for (int c = 0; c < 4; c++) {
        s[r][c] = __expf(s[r][c] - mn);
        rs += s[r][c];
      }
      rs += __shfl_xor(rs, 1);
      rs += __shfl_xor(rs, 2);
      rs += __shfl_xor(rs, 4);
      rs += __shfl_xor(rs, 8);
      lsum[r] = lsum[r] * sc + rs;
      acc[r][0] *= sc;
      acc[r][1] *= sc;
      *(float4*)&Ps[(ty << 2) + r][tx << 2] = make_float4(s[r][0], s[r][1], s[r][2], s[r][3]);
    }
    __syncthreads();
#pragma unroll 4
    for (int k4 = 0; k4 < 16; k4++) {
      float pv[4][4];
#pragma unroll
      for (int r = 0; r < 4; r++) {
        float4 p4 = *(const float4*)&Ps[(ty << 2) + r][k4 << 2];
        pv[r][0] = p4.x; pv[r][1] = p4.y; pv[r][2] = p4.z; pv[r][3] = p4.w;
      }
#pragma unroll
      for (int j = 0; j < 4; j++) {
        float2 v = *(const float2*)&Vs[(k4 << 2) + j][tx << 1];
#pragma unroll
        for (int r = 0; r < 4; r++) {
          acc[r][0] += pv[r][j] * v.x;
          acc[r][1] += pv[r][j] * v.y;
        }
      }
    }
  }
  ushort* op = o + ((size_t)(b * NQR + qt * 64)) * 256 + h * 32;
#pragma unroll
  for (int r = 0; r < 4; r++) {
    float inv = 1.0f / lsum[r];
    ushort2 st;
    st.x = f2b(acc[r][0] * inv);
    st.y = f2b(acc[r][1] * inv);
    *(ushort2*)(op + (size_t)((ty << 2) + r) * 256 + (tx << 1)) = st;
  }
}

// ---------------- reference points: sigmoid(q2 @ ref_w^T + ref_b), bf16 q ----------------
__global__ __launch_bounds__(256) void ref_kernel(
    const ushort* __restrict__ q2, const float* __restrict__ rw,
    const float* __restrict__ rb, float* __restrict__ refo) {
  int lane = threadIdx.x & 63;
  int row = (blockIdx.x << 2) + (threadIdx.x >> 6);
  ushort4 xr = ((const ushort4*)(q2 + (size_t)row * 256))[lane];
  float x0 = b2f(xr.x), x1 = b2f(xr.y), x2 = b2f(xr.z), x3 = b2f(xr.w);
  float4 w0 = ((const float4*)rw)[lane];
  float4 w1 = ((const float4*)(rw + 256))[lane];
  float d0 = x0 * w0.x + x1 * w0.y + x2 * w0.z + x3 * w0.w;
  float d1 = x0 * w1.x + x1 * w1.y + x2 * w1.z + x3 * w1.w;
#pragma unroll
  for (int off = 32; off; off >>= 1) {
    d0 += __shfl_xor(d0, off);
    d1 += __shfl_xor(d1, off);
  }
  if (lane == 0) {
    refo[row * 2 + 0] = 1.0f / (1.0f + __expf(-(d0 + rb[0])));
    refo[row * 2 + 1] = 1.0f / (1.0f + __expf(-(d1 + rb[1])));
  }
}

// ---------------- msdeform sampling: block per (b,q), bf16 value, bf16 out ----------------
__global__ __launch_bounds__(256) void msdeform_kernel(
    const ushort* __restrict__ value, const float* __restrict__ ref,
    const float* __restrict__ off, const float* __restrict__ aw_raw,
    ushort* __restrict__ out) {
  int bq = blockIdx.x;
  int b = bq >> 10;
  __shared__ float s_aw[192], s_lx[192], s_ly[192];
  __shared__ int s_x0[192], s_y0[192];
  int t = threadIdx.x;
  if (t < 192) {
    s_aw[t] = aw_raw[(size_t)bq * 192 + t];
    int l = (t % 24) >> 3;
    float dim = (l == 0) ? 128.f : ((l == 1) ? 64.f : 32.f);
    float rx = ref[bq * 2 + 0], ry = ref[bq * 2 + 1];
    float ox = off[(size_t)bq * 384 + t * 2 + 0];
    float oy = off[(size_t)bq * 384 + t * 2 + 1];
    float gx = rx * dim + ox - 0.5f;
    float gy = ry * dim + oy - 0.5f;
    float fx = floorf(gx), fy = floorf(gy);
    s_x0[t] = (int)fx;
    s_y0[t] = (int)fy;
    s_lx[t] = gx - fx;
    s_ly[t] = gy - fy;
  }
  __syncthreads();
  if (t < 8) {
    float m = -1e30f;
#pragma unroll
    for (int i = 0; i < 24; i++) m = fmaxf(m, s_aw[t * 24 + i]);
    float sm = 0.f;
#pragma unroll
    for (int i = 0; i < 24; i++) {
      float e = __expf(s_aw[t * 24 + i] - m);
      s_aw[t * 24 + i] = e;
      sm += e;
    }
    float inv = 1.0f / sm;
#pragma unroll
    for (int i = 0; i < 24; i++) s_aw[t * 24 + i] *= inv;
  }
  __syncthreads();
  int h = t >> 5, d = t & 31;
  float acc = 0.f;
  const ushort* vb = value + (size_t)b * SROWS * 256 + h * 32 + d;
#pragma unroll
  for (int l = 0; l < 3; l++) {
    int start = (l == 0) ? 0 : ((l == 1) ? 16384 : 20480);
    int dim = (l == 0) ? 128 : ((l == 1) ? 64 : 32);
    const ushort* vl = vb + (size_t)start * 256;
#pragma unroll
    for (int p = 0; p < 8; p++) {
      int e = h * 24 + l * 8 + p;
      float w = s_aw[e];
      int x0 = s_x0[e], y0 = s_y0[e];
      float lx = s_lx[e], ly = s_ly[e];
      float v00 = 0.f, v01 = 0.f, v10 = 0.f, v11 = 0.f;
      bool xin0 = (x0 >= 0) & (x0 < dim);
      bool xin1 = (x0 + 1 >= 0) & (x0 + 1 < dim);
      bool yin0 = (y0 >= 0) & (y0 < dim);
      bool yin1 = (y0 + 1 >= 0) & (y0 + 1 < dim);
      if (yin0 && xin0) v00 = b2f(vl[(size_t)(y0 * dim + x0) * 256]);
      if (yin0 && xin1) v01 = b2f(vl[(size_t)(y0 * dim + x0 + 1) * 256]);
      if (yin1 && xin0) v10 = b2f(vl[(size_t)((y0 + 1) * dim + x0) * 256]);
      if (yin1 && xin1) v11 = b2f(vl[(size_t)((y0 + 1) * dim + x0 + 1) * 256]);
      acc += w * (v00 * (1.f - lx) * (1.f - ly) + v01 * lx * (1.f - ly) +
                  v10 * (1.f - lx) * ly + v11 * lx * ly);
    }
  }
  out[(size_t)bq * 256 + t] = f2b(acc);
}

extern "C" void kernel_launch(void* const* d_in, const int* in_sizes, int n_in,
                              void* d_out, int out_size, void* d_ws, size_t ws_size,
                              hipStream_t stream) {
  const float* tgt = (const float*)d_in[0];
  const float* memory = (const float*)d_in[1];
  const float* n1_w = (const float*)d_in[2];
  const float* n1_b = (const float*)d_in[3];
  const float* attn_in_w = (const float*)d_in[4];
  const float* attn_in_b = (const float*)d_in[5];
  const float* attn_out_w = (const float*)d_in[6];
  const float* attn_out_b = (const float*)d_in[7];
  const float* n2_w = (const float*)d_in[8];
  const float* n2_b = (const float*)d_in[9];
  const float* ref_w = (const float*)d_in[10];
  const float* ref_b = (const float*)d_in[11];
  const float* so_w = (const float*)d_in[12];
  const float* so_b = (const float*)d_in[13];
  const float* aw_w = (const float*)d_in[14];
  const float* aw_b = (const float*)d_in[15];
  const float* vp_w = (const float*)d_in[16];
  const float* vp_b = (const float*)d_in[17];
  const float* op_w = (const float*)d_in[18];
  const float* op_b = (const float*)d_in[19];
  const float* n3_w = (const float*)d_in[20];
  const float* n3_b = (const float*)d_in[21];
  const float* l1_w = (const float*)d_in[22];
  const float* l1_b = (const float*)d_in[23];
  const float* l2_w = (const float*)d_in[24];
  const float* l2_b = (const float*)d_in[25];
  float* out = (float*)d_out;

  // workspace layout (bytes)
  char* base = (char*)d_ws;
  float* bufQKV = (float*)base;                    // 25,165,824 (fp32 qkv; union w/ ff1_bf)
  float* off_buf = (float*)(base + 25165824);      // 12,582,912
  float* aw_buf = (float*)(base + 37748736);       //  6,291,456
  float* ref_buf = (float*)(base + 44040192);      //     65,536
  ushort* q_bf = (ushort*)(base + 44105728);       //  4,194,304
  ushort* mha_bf = (ushort*)(base + 48300032);     //  4,194,304
  ushort* samp_bf = (ushort*)(base + 52494336);    //  4,194,304
  ushort* mem_bf = (ushort*)(base + 56688640);     // 88,080,384
  ushort* val_bf = (ushort*)(base + 144769024);    // 88,080,384
  ushort* wts = (ushort*)(base + 232849408);       //  2,129,920  -> total ~235 MB
  ushort* ff1_bf = (ushort*)bufQKV;                // union: FFN phase only

  ushort* w_attn_in = wts;               // 196608
  ushort* w_attn_out = wts + 196608;     // 65536
  ushort* w_so = wts + 262144;           // 98304
  ushort* w_aw = wts + 360448;           // 49152
  ushort* w_vp = wts + 409600;           // 65536
  ushort* w_op = wts + 475136;           // 65536
  ushort* w_l1 = wts + 540672;           // 262144
  ushort* w_l2 = wts + 802816;           // 262144

  const int NR = 8192;

  // ---- pre-convert weights + memory to bf16 ----
  f2bf_kernel<<<21504, 256, 0, stream>>>(memory, mem_bf);
  f2bf_kernel<<<96, 256, 0, stream>>>(attn_in_w, w_attn_in);
  f2bf_kernel<<<32, 256, 0, stream>>>(attn_out_w, w_attn_out);
  f2bf_kernel<<<48, 256, 0, stream>>>(so_w, w_so);
  f2bf_kernel<<<24, 256, 0, stream>>>(aw_w, w_aw);
  f2bf_kernel<<<32, 256, 0, stream>>>(vp_w, w_vp);
  f2bf_kernel<<<32, 256, 0, stream>>>(op_w, w_op);
  f2bf_kernel<<<128, 256, 0, stream>>>(l1_w, w_l1);
  f2bf_kernel<<<128, 256, 0, stream>>>(l2_w, w_l2);

  // ---- self-attention block ----
  ln_kernel<<<NR / 4, 256, 0, stream>>>(tgt, n1_w, n1_b, q_bf);
  gemm_bf16<false, false, false><<<dim3(NR / 128, 768 / 64), 256, 0, stream>>>(
      (const short*)q_bf, (const short*)w_attn_in, attn_in_b, nullptr, bufQKV, NR, 768, 256);
  attn_tiled<<<dim3(16, 64), 256, 0, stream>>>(bufQKV, mha_bf);
  gemm_bf16<false, true, false><<<dim3(NR / 128, 256 / 64), 256, 0, stream>>>(
      (const short*)mha_bf, (const short*)w_attn_out, attn_out_b, tgt, out, NR, 256, 256);

  // ---- deformable cross-attention block ----
  ln_kernel<<<NR / 4, 256, 0, stream>>>(out, n2_w, n2_b, q_bf);
  gemm_bf16<false, false, true><<<dim3(8 * SROWS / 128, 256 / 64), 256, 0, stream>>>(
      (const short*)mem_bf, (const short*)w_vp, vp_b, nullptr, val_bf, 8 * SROWS, 256, 256);
  ref_kernel<<<NR / 4, 256, 0, stream>>>(q_bf, ref_w, ref_b, ref_buf);
  gemm_bf16<false, false, false><<<dim3(NR / 128, 384 / 64), 256, 0, stream>>>(
      (const short*)q_bf, (const short*)w_so, so_b, nullptr, off_buf, NR, 384, 256);
  gemm_bf16<false, false, false><<<dim3(NR / 128, 192 / 64), 256, 0, stream>>>(
      (const short*)q_bf, (const short*)w_aw, aw_b, nullptr, aw_buf, NR, 192, 256);
  msdeform_kernel<<<NR, 256, 0, stream>>>(val_bf, ref_buf, off_buf, aw_buf, samp_bf);
  gemm_bf16<false, true, false><<<dim3(NR / 128, 256 / 64), 256, 0, stream>>>(
      (const short*)samp_bf, (const short*)w_op, op_b, out, out, NR, 256, 256);

  // ---- FFN block ----
  ln_kernel<<<NR / 4, 256, 0, stream>>>(out, n3_w, n3_b, q_bf);
  gemm_bf16<true, false, true><<<dim3(NR / 128, 1024 / 64), 256, 0, stream>>>(
      (const short*)q_bf, (const short*)w_l1, l1_b, nullptr, ff1_bf, NR, 1024, 256);
  gemm_bf16<false, true, false><<<dim3(NR / 128, 256 / 64), 256, 0, stream>>>(
      (const short*)ff1_bf, (const short*)w_l2, l2_b, out, out, NR, 256, 1024);
}

// Round 5
// 912.821 us; speedup vs baseline: 3.1012x; 1.1204x over previous
//
#include <hip/hip_runtime.h>
#include <math.h>

#define NQR 1024
#define CDIM 256
#define SROWS 21504
#define ATTN_SCALE 0.17677669529663687f

typedef __attribute__((ext_vector_type(8))) short bf16x8;
typedef __attribute__((ext_vector_type(4))) float f32x4;

__device__ __forceinline__ ushort f2b(float x) {  // fp32 -> bf16 bits, RNE
  unsigned u = __float_as_uint(x);
  u += 0x7FFFu + ((u >> 16) & 1u);
  return (ushort)(u >> 16);
}
__device__ __forceinline__ float b2f(ushort b) {
  return __uint_as_float(((unsigned)b) << 16);
}

// ---------------- fp32 -> bf16 elementwise convert (n multiple of 2048) ----------------
__global__ __launch_bounds__(256) void f2bf_kernel(
    const float* __restrict__ x, ushort* __restrict__ y) {
  int i = blockIdx.x * 256 + threadIdx.x;  // each thread: 8 elements
  float4 v0 = ((const float4*)x)[i * 2];
  float4 v1 = ((const float4*)x)[i * 2 + 1];
  ushort4 o0, o1;
  o0.x = f2b(v0.x); o0.y = f2b(v0.y); o0.z = f2b(v0.z); o0.w = f2b(v0.w);
  o1.x = f2b(v1.x); o1.y = f2b(v1.y); o1.z = f2b(v1.z); o1.w = f2b(v1.w);
  ((ushort4*)y)[i * 2] = o0;
  ((ushort4*)y)[i * 2 + 1] = o1;
}

// ---------------- LayerNorm: one wave per 256-wide row, bf16 out ----------------
__global__ __launch_bounds__(256) void ln_kernel(
    const float* __restrict__ x, const float* __restrict__ w,
    const float* __restrict__ b, ushort* __restrict__ y) {
  int lane = threadIdx.x & 63;
  int row = (blockIdx.x << 2) + (threadIdx.x >> 6);
  float4 v = ((const float4*)(x + (size_t)row * CDIM))[lane];
  float s = v.x + v.y + v.z + v.w;
  float ss = v.x * v.x + v.y * v.y + v.z * v.z + v.w * v.w;
#pragma unroll
  for (int off = 32; off; off >>= 1) {
    s += __shfl_xor(s, off);
    ss += __shfl_xor(ss, off);
  }
  float m = s * (1.0f / 256.0f);
  float var = ss * (1.0f / 256.0f) - m * m;
  float r = rsqrtf(var + 1e-5f);
  float4 wv = ((const float4*)w)[lane];
  float4 bv = ((const float4*)b)[lane];
  ushort4 o;
  o.x = f2b((v.x - m) * r * wv.x + bv.x);
  o.y = f2b((v.y - m) * r * wv.y + bv.y);
  o.z = f2b((v.z - m) * r * wv.z + bv.z);
  o.w = f2b((v.w - m) * r * wv.w + bv.w);
  ((ushort4*)(y + (size_t)row * CDIM))[lane] = o;
}

// ---------------- bf16 MFMA GEMM: C[M,N] = A[M,K] @ W[N,K]^T + bias (+gelu, +res) ----
template <bool GELU, bool RES, bool OUTBF>
__global__ __launch_bounds__(256) void gemm_bf16(
    const short* __restrict__ A, const short* __restrict__ W,
    const float* __restrict__ bias, const float* __restrict__ res,
    void* __restrict__ Cout, int M, int N, int K) {
  __shared__ short As[128 * 72];
  __shared__ short Bs[64 * 72];
  int t = threadIdx.x;
  int l = t & 63;
  int wave = t >> 6;
  int wm = wave >> 1, wn = wave & 1;
  int lrow = t >> 3;        // 0..31
  int lcol = (t & 7) << 3;  // 0..56
  size_t m0 = (size_t)blockIdx.x * 128;
  int n0 = blockIdx.y * 64;
  const short* Ag = A + (m0 + lrow) * K + lcol;
  const short* Wg = W + (size_t)(n0 + lrow) * K + lcol;
  f32x4 acc[4][2] = {};
  int fr = l & 15, fq = l >> 4;
  for (int k0 = 0; k0 < K; k0 += 64) {
    uint4 a0 = *(const uint4*)(Ag + k0);
    uint4 a1 = *(const uint4*)(Ag + (size_t)32 * K + k0);
    uint4 a2 = *(const uint4*)(Ag + (size_t)64 * K + k0);
    uint4 a3 = *(const uint4*)(Ag + (size_t)96 * K + k0);
    uint4 b0 = *(const uint4*)(Wg + k0);
    uint4 b1 = *(const uint4*)(Wg + (size_t)32 * K + k0);
    __syncthreads();
    *(uint4*)&As[lrow * 72 + lcol] = a0;
    *(uint4*)&As[(lrow + 32) * 72 + lcol] = a1;
    *(uint4*)&As[(lrow + 64) * 72 + lcol] = a2;
    *(uint4*)&As[(lrow + 96) * 72 + lcol] = a3;
    *(uint4*)&Bs[lrow * 72 + lcol] = b0;
    *(uint4*)&Bs[(lrow + 32) * 72 + lcol] = b1;
    __syncthreads();
#pragma unroll
    for (int kk = 0; kk < 2; kk++) {
      int kb = kk * 32 + fq * 8;
      bf16x8 af[4], bfr[2];
#pragma unroll
      for (int mi = 0; mi < 4; mi++)
        af[mi] = *(const bf16x8*)&As[(wm * 64 + mi * 16 + fr) * 72 + kb];
#pragma unroll
      for (int ni = 0; ni < 2; ni++)
        bfr[ni] = *(const bf16x8*)&Bs[(wn * 32 + ni * 16 + fr) * 72 + kb];
#pragma unroll
      for (int mi = 0; mi < 4; mi++)
#pragma unroll
        for (int ni = 0; ni < 2; ni++)
          acc[mi][ni] = __builtin_amdgcn_mfma_f32_16x16x32_bf16(
              af[mi], bfr[ni], acc[mi][ni], 0, 0, 0);
    }
  }
#pragma unroll
  for (int ni = 0; ni < 2; ni++) {
    int gcol = n0 + wn * 32 + ni * 16 + fr;
    float bv = bias[gcol];
#pragma unroll
    for (int mi = 0; mi < 4; mi++) {
#pragma unroll
      for (int j = 0; j < 4; j++) {
        size_t grow = m0 + wm * 64 + mi * 16 + fq * 4 + j;
        float v = acc[mi][ni][j] + bv;
        if (GELU) v = 0.5f * v * (1.0f + erff(v * 0.70710678118654752f));
        if (RES) v += res[grow * N + gcol];
        if (OUTBF)
          ((ushort*)Cout)[grow * N + gcol] = f2b(v);
        else
          ((float*)Cout)[grow * N + gcol] = v;
      }
    }
  }
}

// ---------------- Flash-style tiled MHA (fp32 in, bf16 out) ----------------
__global__ __launch_bounds__(256) void attn_tiled(
    const float* __restrict__ qkv, ushort* __restrict__ o) {
  __shared__ float QsT[32][68];
  __shared__ float KsT[32][68];
  __shared__ float Vs[64][36];
  __shared__ float Ps[64][68];
  int qt = blockIdx.x;
  int bh = blockIdx.y;
  int b = bh >> 3, h = bh & 7;
  int t = threadIdx.x;
  int tx = t & 15, ty = t >> 4;
  int lr = t >> 2;
  int lc = (t & 3) << 2;

  {
    const float* qp = qkv + ((size_t)(b * NQR + qt * 64 + lr)) * 768 + h * 32;
    float4 a = *(const float4*)(qp + lc);
    float4 b4 = *(const float4*)(qp + lc + 16);
    QsT[lc + 0][lr] = a.x * ATTN_SCALE;
    QsT[lc + 1][lr] = a.y * ATTN_SCALE;
    QsT[lc + 2][lr] = a.z * ATTN_SCALE;
    QsT[lc + 3][lr] = a.w * ATTN_SCALE;
    QsT[lc + 16][lr] = b4.x * ATTN_SCALE;
    QsT[lc + 17][lr] = b4.y * ATTN_SCALE;
    QsT[lc + 18][lr] = b4.z * ATTN_SCALE;
    QsT[lc + 19][lr] = b4.w * ATTN_SCALE;
  }
  float m[4] = {-1e30f, -1e30f, -1e30f, -1e30f};
  float lsum[4] = {0.f, 0.f, 0.f, 0.f};
  float acc[4][2] = {};

  for (int kt = 0; kt < 16; kt++) {
    const float* kp = qkv + ((size_t)(b * NQR + kt * 64 + lr)) * 768 + 256 + h * 32;
    float4 k0 = *(const float4*)(kp + lc);
    float4 k1 = *(const float4*)(kp + lc + 16);
    const float* vp = kp + 256;
    float4 w0 = *(const float4*)(vp + lc);
    float4 w1 = *(const float4*)(vp + lc + 16);
    __syncthreads();
    KsT[lc + 0][lr] = k0.x;
    KsT[lc + 1][lr] = k0.y;
    KsT[lc + 2][lr] = k0.z;
    KsT[lc + 3][lr] = k0.w;
    KsT[lc + 16][lr] = k1.x;
    KsT[lc + 17][lr] = k1.y;
    KsT[lc + 18][lr] = k1.z;
    KsT[lc + 19][lr] = k1.w;
    *(float4*)&Vs[lr][lc] = w0;
    *(float4*)&Vs[lr][lc + 16] = w1;
    __syncthreads();
    float s[4][4] = {};
#pragma unroll
    for (int d = 0; d < 32; d++) {
      float4 a = *(const float4*)&QsT[d][ty << 2];
      float4 k = *(const float4*)&KsT[d][tx << 2];
      s[0][0] += a.x * k.x; s[0][1] += a.x * k.y; s[0][2] += a.x * k.z; s[0][3] += a.x * k.w;
      s[1][0] += a.y * k.x; s[1][1] += a.y * k.y; s[1][2] += a.y * k.z; s[1][3] += a.y * k.w;
      s[2][0] += a.z * k.x; s[2][1] += a.z * k.y; s[2][2] += a.z * k.z; s[2][3] += a.z * k.w;
      s[3][0] += a.w * k.x; s[3][1] += a.w * k.y; s[3][2] += a.w * k.z; s[3][3] += a.w * k.w;
    }
#pragma unroll
    for (int r = 0; r < 4; r++) {
      float mt = fmaxf(fmaxf(s[r][0], s[r][1]), fmaxf(s[r][2], s[r][3]));
      mt = fmaxf(mt, __shfl_xor(mt, 1));
      mt = fmaxf(mt, __shfl_xor(mt, 2));
      mt = fmaxf(mt, __shfl_xor(mt, 4));
      mt = fmaxf(mt, __shfl_xor(mt, 8));
      float mn = fmaxf(m[r], mt);
      float sc = __expf(m[r] - mn);
      m[r] = mn;
      float rs = 0.f;
#pragma unroll
      for (int c = 0; c < 4; c++) {
        s[r][c] = __expf(s[r][c] - mn);
        rs += s[r][c];
      }
      rs += __shfl_xor(rs, 1);
      rs += __shfl_xor(rs, 2);
      rs += __shfl_xor(rs, 4);
      rs += __shfl_xor(rs, 8);
      lsum[r] = lsum[r] * sc + rs;
      acc[r][0] *= sc;
      acc[r][1] *= sc;
      *(float4*)&Ps[(ty << 2) + r][tx << 2] = make_float4(s[r][0], s[r][1], s[r][2], s[r][3]);
    }
    __syncthreads();
#pragma unroll 4
    for (int k4 = 0; k4 < 16; k4++) {
      float pv[4][4];
#pragma unroll
      for (int r = 0; r < 4; r++) {
        float4 p4 = *(const float4*)&Ps[(ty << 2) + r][k4 << 2];
        pv[r][0] = p4.x; pv[r][1] = p4.y; pv[r][2] = p4.z; pv[r][3] = p4.w;
      }
#pragma unroll
      for (int j = 0; j < 4; j++) {
        float2 v = *(const float2*)&Vs[(k4 << 2) + j][tx << 1];
#pragma unroll
        for (int r = 0; r < 4; r++) {
          acc[r][0] += pv[r][j] * v.x;
          acc[r][1] += pv[r][j] * v.y;
        }
      }
    }
  }
  ushort* op = o + ((size_t)(b * NQR + qt * 64)) * 256 + h * 32;
#pragma unroll
  for (int r = 0; r < 4; r++) {
    float inv = 1.0f / lsum[r];
    ushort2 st;
    st.x = f2b(acc[r][0] * inv);
    st.y = f2b(acc[r][1] * inv);
    *(ushort2*)(op + (size_t)((ty << 2) + r) * 256 + (tx << 1)) = st;
  }
}

// ---------------- reference points: sigmoid(q2 @ ref_w^T + ref_b), bf16 q ----------------
__global__ __launch_bounds__(256) void ref_kernel(
    const ushort* __restrict__ q2, const float* __restrict__ rw,
    const float* __restrict__ rb, float* __restrict__ refo) {
  int lane = threadIdx.x & 63;
  int row = (blockIdx.x << 2) + (threadIdx.x >> 6);
  ushort4 xr = ((const ushort4*)(q2 + (size_t)row * 256))[lane];
  float x0 = b2f(xr.x), x1 = b2f(xr.y), x2 = b2f(xr.z), x3 = b2f(xr.w);
  float4 w0 = ((const float4*)rw)[lane];
  float4 w1 = ((const float4*)(rw + 256))[lane];
  float d0 = x0 * w0.x + x1 * w0.y + x2 * w0.z + x3 * w0.w;
  float d1 = x0 * w1.x + x1 * w1.y + x2 * w1.z + x3 * w1.w;
#pragma unroll
  for (int off = 32; off; off >>= 1) {
    d0 += __shfl_xor(d0, off);
    d1 += __shfl_xor(d1, off);
  }
  if (lane == 0) {
    refo[row * 2 + 0] = 1.0f / (1.0f + __expf(-(d0 + rb[0])));
    refo[row * 2 + 1] = 1.0f / (1.0f + __expf(-(d1 + rb[1])));
  }
}

// ---------------- msdeform sampling: block = 4 queries, thread = (qq,h,dgroup4) ----------
// ushort4 (8B) gathers: 4x fewer VMEM instructions, 4x bytes/instr vs scalar ushort.
__global__ __launch_bounds__(256) void msdeform_kernel(
    const ushort* __restrict__ value, const float* __restrict__ ref,
    const float* __restrict__ off, const float* __restrict__ aw_raw,
    ushort* __restrict__ out) {
  int q0 = blockIdx.x << 2;  // 4 queries per block
  __shared__ float s_aw[4][192], s_lx[4][192], s_ly[4][192];
  __shared__ int s_x0[4][192], s_y0[4][192];
  int t = threadIdx.x;
  // prep 768 = 4q x 192 entries
#pragma unroll
  for (int i = 0; i < 3; i++) {
    int e = t + 256 * i;
    int qq = e / 192, ee = e - qq * 192;
    int bq = q0 + qq;
    s_aw[qq][ee] = aw_raw[(size_t)bq * 192 + ee];
    int l = (ee % 24) >> 3;
    float dim = (l == 0) ? 128.f : ((l == 1) ? 64.f : 32.f);
    float rx = ref[bq * 2 + 0], ry = ref[bq * 2 + 1];
    float ox = off[(size_t)bq * 384 + ee * 2 + 0];
    float oy = off[(size_t)bq * 384 + ee * 2 + 1];
    float gx = rx * dim + ox - 0.5f;
    float gy = ry * dim + oy - 0.5f;
    float fx = floorf(gx), fy = floorf(gy);
    s_x0[qq][ee] = (int)fx;
    s_y0[qq][ee] = (int)fy;
    s_lx[qq][ee] = gx - fx;
    s_ly[qq][ee] = gy - fy;
  }
  __syncthreads();
  if (t < 32) {  // softmax over 24 per (qq,h)
    int qq = t >> 3, h = t & 7;
    float* a = &s_aw[qq][h * 24];
    float m = -1e30f;
#pragma unroll
    for (int i = 0; i < 24; i++) m = fmaxf(m, a[i]);
    float sm = 0.f;
#pragma unroll
    for (int i = 0; i < 24; i++) {
      float e = __expf(a[i] - m);
      a[i] = e;
      sm += e;
    }
    float inv = 1.0f / sm;
#pragma unroll
    for (int i = 0; i < 24; i++) a[i] *= inv;
  }
  __syncthreads();
  int qq = t >> 6;            // wave id = query
  int h = (t >> 3) & 7;       // 8 heads
  int dg = t & 7;             // d-group: d = 4*dg .. 4*dg+3
  int bq = q0 + qq;
  int b = bq >> 10;
  float acc0 = 0.f, acc1 = 0.f, acc2 = 0.f, acc3 = 0.f;
  const ushort* vb = value + (size_t)b * SROWS * 256 + h * 32 + dg * 4;
#pragma unroll
  for (int l = 0; l < 3; l++) {
    int start = (l == 0) ? 0 : ((l == 1) ? 16384 : 20480);
    int dim = (l == 0) ? 128 : ((l == 1) ? 64 : 32);
    const ushort* vl = vb + (size_t)start * 256;
#pragma unroll
    for (int p = 0; p < 8; p++) {
      int e = h * 24 + l * 8 + p;
      float w = s_aw[qq][e];
      int x0 = s_x0[qq][e], y0 = s_y0[qq][e];
      float lx = s_lx[qq][e], ly = s_ly[qq][e];
      bool xin0 = (x0 >= 0) & (x0 < dim);
      bool xin1 = (x0 + 1 >= 0) & (x0 + 1 < dim);
      bool yin0 = (y0 >= 0) & (y0 < dim);
      bool yin1 = (y0 + 1 >= 0) & (y0 + 1 < dim);
      ushort4 u00 = {0, 0, 0, 0}, u01 = {0, 0, 0, 0}, u10 = {0, 0, 0, 0}, u11 = {0, 0, 0, 0};
      if (yin0 && xin0) u00 = *(const ushort4*)(vl + (size_t)(y0 * dim + x0) * 256);
      if (yin0 && xin1) u01 = *(const ushort4*)(vl + (size_t)(y0 * dim + x0 + 1) * 256);
      if (yin1 && xin0) u10 = *(const ushort4*)(vl + (size_t)((y0 + 1) * dim + x0) * 256);
      if (yin1 && xin1) u11 = *(const ushort4*)(vl + (size_t)((y0 + 1) * dim + x0 + 1) * 256);
      float w00 = w * (1.f - lx) * (1.f - ly);
      float w01 = w * lx * (1.f - ly);
      float w10 = w * (1.f - lx) * ly;
      float w11 = w * lx * ly;
      acc0 += b2f(u00.x) * w00 + b2f(u01.x) * w01 + b2f(u10.x) * w10 + b2f(u11.x) * w11;
      acc1 += b2f(u00.y) * w00 + b2f(u01.y) * w01 + b2f(u10.y) * w10 + b2f(u11.y) * w11;
      acc2 += b2f(u00.z) * w00 + b2f(u01.z) * w01 + b2f(u10.z) * w10 + b2f(u11.z) * w11;
      acc3 += b2f(u00.w) * w00 + b2f(u01.w) * w01 + b2f(u10.w) * w10 + b2f(u11.w) * w11;
    }
  }
  ushort4 o4;
  o4.x = f2b(acc0);
  o4.y = f2b(acc1);
  o4.z = f2b(acc2);
  o4.w = f2b(acc3);
  *(ushort4*)(out + (size_t)bq * 256 + h * 32 + dg * 4) = o4;
}

extern "C" void kernel_launch(void* const* d_in, const int* in_sizes, int n_in,
                              void* d_out, int out_size, void* d_ws, size_t ws_size,
                              hipStream_t stream) {
  const float* tgt = (const float*)d_in[0];
  const float* memory = (const float*)d_in[1];
  const float* n1_w = (const float*)d_in[2];
  const float* n1_b = (const float*)d_in[3];
  const float* attn_in_w = (const float*)d_in[4];
  const float* attn_in_b = (const float*)d_in[5];
  const float* attn_out_w = (const float*)d_in[6];
  const float* attn_out_b = (const float*)d_in[7];
  const float* n2_w = (const float*)d_in[8];
  const float* n2_b = (const float*)d_in[9];
  const float* ref_w = (const float*)d_in[10];
  const float* ref_b = (const float*)d_in[11];
  const float* so_w = (const float*)d_in[12];
  const float* so_b = (const float*)d_in[13];
  const float* aw_w = (const float*)d_in[14];
  const float* aw_b = (const float*)d_in[15];
  const float* vp_w = (const float*)d_in[16];
  const float* vp_b = (const float*)d_in[17];
  const float* op_w = (const float*)d_in[18];
  const float* op_b = (const float*)d_in[19];
  const float* n3_w = (const float*)d_in[20];
  const float* n3_b = (const float*)d_in[21];
  const float* l1_w = (const float*)d_in[22];
  const float* l1_b = (const float*)d_in[23];
  const float* l2_w = (const float*)d_in[24];
  const float* l2_b = (const float*)d_in[25];
  float* out = (float*)d_out;

  // workspace layout (bytes)
  char* base = (char*)d_ws;
  float* bufQKV = (float*)base;                    // 25,165,824 (fp32 qkv; union w/ ff1_bf)
  float* off_buf = (float*)(base + 25165824);      // 12,582,912
  float* aw_buf = (float*)(base + 37748736);       //  6,291,456
  float* ref_buf = (float*)(base + 44040192);      //     65,536
  ushort* q_bf = (ushort*)(base + 44105728);       //  4,194,304
  ushort* mha_bf = (ushort*)(base + 48300032);     //  4,194,304
  ushort* samp_bf = (ushort*)(base + 52494336);    //  4,194,304
  ushort* mem_bf = (ushort*)(base + 56688640);     // 88,080,384
  ushort* val_bf = (ushort*)(base + 144769024);    // 88,080,384
  ushort* wts = (ushort*)(base + 232849408);       //  2,129,920  -> total ~235 MB
  ushort* ff1_bf = (ushort*)bufQKV;                // union: FFN phase only

  ushort* w_attn_in = wts;               // 196608
  ushort* w_attn_out = wts + 196608;     // 65536
  ushort* w_so = wts + 262144;           // 98304
  ushort* w_aw = wts + 360448;           // 49152
  ushort* w_vp = wts + 409600;           // 65536
  ushort* w_op = wts + 475136;           // 65536
  ushort* w_l1 = wts + 540672;           // 262144
  ushort* w_l2 = wts + 802816;           // 262144

  const int NR = 8192;

  // ---- pre-convert weights + memory to bf16 ----
  f2bf_kernel<<<21504, 256, 0, stream>>>(memory, mem_bf);
  f2bf_kernel<<<96, 256, 0, stream>>>(attn_in_w, w_attn_in);
  f2bf_kernel<<<32, 256, 0, stream>>>(attn_out_w, w_attn_out);
  f2bf_kernel<<<48, 256, 0, stream>>>(so_w, w_so);
  f2bf_kernel<<<24, 256, 0, stream>>>(aw_w, w_aw);
  f2bf_kernel<<<32, 256, 0, stream>>>(vp_w, w_vp);
  f2bf_kernel<<<32, 256, 0, stream>>>(op_w, w_op);
  f2bf_kernel<<<128, 256, 0, stream>>>(l1_w, w_l1);
  f2bf_kernel<<<128, 256, 0, stream>>>(l2_w, w_l2);

  // ---- self-attention block ----
  ln_kernel<<<NR / 4, 256, 0, stream>>>(tgt, n1_w, n1_b, q_bf);
  gemm_bf16<false, false, false><<<dim3(NR / 128, 768 / 64), 256, 0, stream>>>(
      (const short*)q_bf, (const short*)w_attn_in, attn_in_b, nullptr, bufQKV, NR, 768, 256);
  attn_tiled<<<dim3(16, 64), 256, 0, stream>>>(bufQKV, mha_bf);
  gemm_bf16<false, true, false><<<dim3(NR / 128, 256 / 64), 256, 0, stream>>>(
      (const short*)mha_bf, (const short*)w_attn_out, attn_out_b, tgt, out, NR, 256, 256);

  // ---- deformable cross-attention block ----
  ln_kernel<<<NR / 4, 256, 0, stream>>>(out, n2_w, n2_b, q_bf);
  gemm_bf16<false, false, true><<<dim3(8 * SROWS / 128, 256 / 64), 256, 0, stream>>>(
      (const short*)mem_bf, (const short*)w_vp, vp_b, nullptr, val_bf, 8 * SROWS, 256, 256);
  ref_kernel<<<NR / 4, 256, 0, stream>>>(q_bf, ref_w, ref_b, ref_buf);
  gemm_bf16<false, false, false><<<dim3(NR / 128, 384 / 64), 256, 0, stream>>>(
      (const short*)q_bf, (const short*)w_so, so_b, nullptr, off_buf, NR, 384, 256);
  gemm_bf16<false, false, false><<<dim3(NR / 128, 192 / 64), 256, 0, stream>>>(
      (const short*)q_bf, (const short*)w_aw, aw_b, nullptr, aw_buf, NR, 192, 256);
  msdeform_kernel<<<NR / 4, 256, 0, stream>>>(val_bf, ref_buf, off_buf, aw_buf, samp_bf);
  gemm_bf16<false, true, false><<<dim3(NR / 128, 256 / 64), 256, 0, stream>>>(
      (const short*)samp_bf, (const short*)w_op, op_b, out, out, NR, 256, 256);

  // ---- FFN block ----
  ln_kernel<<<NR / 4, 256, 0, stream>>>(out, n3_w, n3_b, q_bf);
  gemm_bf16<true, false, true><<<dim3(NR / 128, 1024 / 64), 256, 0, stream>>>(
      (const short*)q_bf, (const short*)w_l1, l1_b, nullptr, ff1_bf, NR, 1024, 256);
  gemm_bf16<false, true, false><<<dim3(NR / 128, 256 / 64), 256, 0, stream>>>(
      (const short*)ff1_bf, (const short*)w_l2, l2_b, out, out, NR, 256, 1024);
}

// Round 6
// 732.805 us; speedup vs baseline: 3.8630x; 1.2457x over previous
//
#include <hip/hip_runtime.h>
#include <math.h>

#define NQR 1024
#define CDIM 256
#define SROWS 21504
#define ATTN_SCALE 0.17677669529663687f

typedef __attribute__((ext_vector_type(8))) short bf16x8;
typedef __attribute__((ext_vector_type(4))) float f32x4;

__device__ __forceinline__ ushort f2b(float x) {  // fp32 -> bf16 bits, RNE
  unsigned u = __float_as_uint(x);
  u += 0x7FFFu + ((u >> 16) & 1u);
  return (ushort)(u >> 16);
}
__device__ __forceinline__ float b2f(ushort b) {
  return __uint_as_float(((unsigned)b) << 16);
}

// ---------------- fp32 -> bf16 elementwise convert (n multiple of 2048) ----------------
__global__ __launch_bounds__(256) void f2bf_kernel(
    const float* __restrict__ x, ushort* __restrict__ y) {
  int i = blockIdx.x * 256 + threadIdx.x;  // each thread: 8 elements
  float4 v0 = ((const float4*)x)[i * 2];
  float4 v1 = ((const float4*)x)[i * 2 + 1];
  ushort4 o0, o1;
  o0.x = f2b(v0.x); o0.y = f2b(v0.y); o0.z = f2b(v0.z); o0.w = f2b(v0.w);
  o1.x = f2b(v1.x); o1.y = f2b(v1.y); o1.z = f2b(v1.z); o1.w = f2b(v1.w);
  ((ushort4*)y)[i * 2] = o0;
  ((ushort4*)y)[i * 2 + 1] = o1;
}

// ---------------- LayerNorm: one wave per 256-wide row, bf16 out ----------------
__global__ __launch_bounds__(256) void ln_kernel(
    const float* __restrict__ x, const float* __restrict__ w,
    const float* __restrict__ b, ushort* __restrict__ y) {
  int lane = threadIdx.x & 63;
  int row = (blockIdx.x << 2) + (threadIdx.x >> 6);
  float4 v = ((const float4*)(x + (size_t)row * CDIM))[lane];
  float s = v.x + v.y + v.z + v.w;
  float ss = v.x * v.x + v.y * v.y + v.z * v.z + v.w * v.w;
#pragma unroll
  for (int off = 32; off; off >>= 1) {
    s += __shfl_xor(s, off);
    ss += __shfl_xor(ss, off);
  }
  float m = s * (1.0f / 256.0f);
  float var = ss * (1.0f / 256.0f) - m * m;
  float r = rsqrtf(var + 1e-5f);
  float4 wv = ((const float4*)w)[lane];
  float4 bv = ((const float4*)b)[lane];
  ushort4 o;
  o.x = f2b((v.x - m) * r * wv.x + bv.x);
  o.y = f2b((v.y - m) * r * wv.y + bv.y);
  o.z = f2b((v.z - m) * r * wv.z + bv.z);
  o.w = f2b((v.w - m) * r * wv.w + bv.w);
  ((ushort4*)(y + (size_t)row * CDIM))[lane] = o;
}

// ---------------- bf16 MFMA GEMM: C[M,N] = A[M,K] @ W[N,K]^T + bias (+gelu, +res) ----
template <bool GELU, bool RES, bool OUTBF>
__global__ __launch_bounds__(256) void gemm_bf16(
    const short* __restrict__ A, const short* __restrict__ W,
    const float* __restrict__ bias, const float* __restrict__ res,
    void* __restrict__ Cout, int M, int N, int K) {
  __shared__ short As[128 * 72];
  __shared__ short Bs[64 * 72];
  int t = threadIdx.x;
  int l = t & 63;
  int wave = t >> 6;
  int wm = wave >> 1, wn = wave & 1;
  int lrow = t >> 3;        // 0..31
  int lcol = (t & 7) << 3;  // 0..56
  size_t m0 = (size_t)blockIdx.x * 128;
  int n0 = blockIdx.y * 64;
  const short* Ag = A + (m0 + lrow) * K + lcol;
  const short* Wg = W + (size_t)(n0 + lrow) * K + lcol;
  f32x4 acc[4][2] = {};
  int fr = l & 15, fq = l >> 4;
  for (int k0 = 0; k0 < K; k0 += 64) {
    uint4 a0 = *(const uint4*)(Ag + k0);
    uint4 a1 = *(const uint4*)(Ag + (size_t)32 * K + k0);
    uint4 a2 = *(const uint4*)(Ag + (size_t)64 * K + k0);
    uint4 a3 = *(const uint4*)(Ag + (size_t)96 * K + k0);
    uint4 b0 = *(const uint4*)(Wg + k0);
    uint4 b1 = *(const uint4*)(Wg + (size_t)32 * K + k0);
    __syncthreads();
    *(uint4*)&As[lrow * 72 + lcol] = a0;
    *(uint4*)&As[(lrow + 32) * 72 + lcol] = a1;
    *(uint4*)&As[(lrow + 64) * 72 + lcol] = a2;
    *(uint4*)&As[(lrow + 96) * 72 + lcol] = a3;
    *(uint4*)&Bs[lrow * 72 + lcol] = b0;
    *(uint4*)&Bs[(lrow + 32) * 72 + lcol] = b1;
    __syncthreads();
#pragma unroll
    for (int kk = 0; kk < 2; kk++) {
      int kb = kk * 32 + fq * 8;
      bf16x8 af[4], bfr[2];
#pragma unroll
      for (int mi = 0; mi < 4; mi++)
        af[mi] = *(const bf16x8*)&As[(wm * 64 + mi * 16 + fr) * 72 + kb];
#pragma unroll
      for (int ni = 0; ni < 2; ni++)
        bfr[ni] = *(const bf16x8*)&Bs[(wn * 32 + ni * 16 + fr) * 72 + kb];
#pragma unroll
      for (int mi = 0; mi < 4; mi++)
#pragma unroll
        for (int ni = 0; ni < 2; ni++)
          acc[mi][ni] = __builtin_amdgcn_mfma_f32_16x16x32_bf16(
              af[mi], bfr[ni], acc[mi][ni], 0, 0, 0);
    }
  }
#pragma unroll
  for (int ni = 0; ni < 2; ni++) {
    int gcol = n0 + wn * 32 + ni * 16 + fr;
    float bv = bias[gcol];
#pragma unroll
    for (int mi = 0; mi < 4; mi++) {
#pragma unroll
      for (int j = 0; j < 4; j++) {
        size_t grow = m0 + wm * 64 + mi * 16 + fq * 4 + j;
        float v = acc[mi][ni][j] + bv;
        if (GELU) v = 0.5f * v * (1.0f + erff(v * 0.70710678118654752f));
        if (RES) v += res[grow * N + gcol];
        if (OUTBF)
          ((ushort*)Cout)[grow * N + gcol] = f2b(v);
        else
          ((float*)Cout)[grow * N + gcol] = v;
      }
    }
  }
}

// ---------------- Flash-style tiled MHA (fp32 in, bf16 out) ----------------
__global__ __launch_bounds__(256) void attn_tiled(
    const float* __restrict__ qkv, ushort* __restrict__ o) {
  __shared__ float QsT[32][68];
  __shared__ float KsT[32][68];
  __shared__ float Vs[64][36];
  __shared__ float Ps[64][68];
  int qt = blockIdx.x;
  int bh = blockIdx.y;
  int b = bh >> 3, h = bh & 7;
  int t = threadIdx.x;
  int tx = t & 15, ty = t >> 4;
  int lr = t >> 2;
  int lc = (t & 3) << 2;

  {
    const float* qp = qkv + ((size_t)(b * NQR + qt * 64 + lr)) * 768 + h * 32;
    float4 a = *(const float4*)(qp + lc);
    float4 b4 = *(const float4*)(qp + lc + 16);
    QsT[lc + 0][lr] = a.x * ATTN_SCALE;
    QsT[lc + 1][lr] = a.y * ATTN_SCALE;
    QsT[lc + 2][lr] = a.z * ATTN_SCALE;
    QsT[lc + 3][lr] = a.w * ATTN_SCALE;
    QsT[lc + 16][lr] = b4.x * ATTN_SCALE;
    QsT[lc + 17][lr] = b4.y * ATTN_SCALE;
    QsT[lc + 18][lr] = b4.z * ATTN_SCALE;
    QsT[lc + 19][lr] = b4.w * ATTN_SCALE;
  }
  float m[4] = {-1e30f, -1e30f, -1e30f, -1e30f};
  float lsum[4] = {0.f, 0.f, 0.f, 0.f};
  float acc[4][2] = {};

  for (int kt = 0; kt < 16; kt++) {
    const float* kp = qkv + ((size_t)(b * NQR + kt * 64 + lr)) * 768 + 256 + h * 32;
    float4 k0 = *(const float4*)(kp + lc);
    float4 k1 = *(const float4*)(kp + lc + 16);
    const float* vp = kp + 256;
    float4 w0 = *(const float4*)(vp + lc);
    float4 w1 = *(const float4*)(vp + lc + 16);
    __syncthreads();
    KsT[lc + 0][lr] = k0.x;
    KsT[lc + 1][lr] = k0.y;
    KsT[lc + 2][lr] = k0.z;
    KsT[lc + 3][lr] = k0.w;
    KsT[lc + 16][lr] = k1.x;
    KsT[lc + 17][lr] = k1.y;
    KsT[lc + 18][lr] = k1.z;
    KsT[lc + 19][lr] = k1.w;
    *(float4*)&Vs[lr][lc] = w0;
    *(float4*)&Vs[lr][lc + 16] = w1;
    __syncthreads();
    float s[4][4] = {};
#pragma unroll
    for (int d = 0; d < 32; d++) {
      float4 a = *(const float4*)&QsT[d][ty << 2];
      float4 k = *(const float4*)&KsT[d][tx << 2];
      s[0][0] += a.x * k.x; s[0][1] += a.x * k.y; s[0][2] += a.x * k.z; s[0][3] += a.x * k.w;
      s[1][0] += a.y * k.x; s[1][1] += a.y * k.y; s[1][2] += a.y * k.z; s[1][3] += a.y * k.w;
      s[2][0] += a.z * k.x; s[2][1] += a.z * k.y; s[2][2] += a.z * k.z; s[2][3] += a.z * k.w;
      s[3][0] += a.w * k.x; s[3][1] += a.w * k.y; s[3][2] += a.w * k.z; s[3][3] += a.w * k.w;
    }
#pragma unroll
    for (int r = 0; r < 4; r++) {
      float mt = fmaxf(fmaxf(s[r][0], s[r][1]), fmaxf(s[r][2], s[r][3]));
      mt = fmaxf(mt, __shfl_xor(mt, 1));
      mt = fmaxf(mt, __shfl_xor(mt, 2));
      mt = fmaxf(mt, __shfl_xor(mt, 4));
      mt = fmaxf(mt, __shfl_xor(mt, 8));
      float mn = fmaxf(m[r], mt);
      float sc = __expf(m[r] - mn);
      m[r] = mn;
      float rs = 0.f;
#pragma unroll
      for (int c = 0; c < 4; c++) {
        s[r][c] = __expf(s[r][c] - mn);
        rs += s[r][c];
      }
      rs += __shfl_xor(rs, 1);
      rs += __shfl_xor(rs, 2);
      rs += __shfl_xor(rs, 4);
      rs += __shfl_xor(rs, 8);
      lsum[r] = lsum[r] * sc + rs;
      acc[r][0] *= sc;
      acc[r][1] *= sc;
      *(float4*)&Ps[(ty << 2) + r][tx << 2] = make_float4(s[r][0], s[r][1], s[r][2], s[r][3]);
    }
    __syncthreads();
#pragma unroll 4
    for (int k4 = 0; k4 < 16; k4++) {
      float pv[4][4];
#pragma unroll
      for (int r = 0; r < 4; r++) {
        float4 p4 = *(const float4*)&Ps[(ty << 2) + r][k4 << 2];
        pv[r][0] = p4.x; pv[r][1] = p4.y; pv[r][2] = p4.z; pv[r][3] = p4.w;
      }
#pragma unroll
      for (int j = 0; j < 4; j++) {
        float2 v = *(const float2*)&Vs[(k4 << 2) + j][tx << 1];
#pragma unroll
        for (int r = 0; r < 4; r++) {
          acc[r][0] += pv[r][j] * v.x;
          acc[r][1] += pv[r][j] * v.y;
        }
      }
    }
  }
  ushort* op = o + ((size_t)(b * NQR + qt * 64)) * 256 + h * 32;
#pragma unroll
  for (int r = 0; r < 4; r++) {
    float inv = 1.0f / lsum[r];
    ushort2 st;
    st.x = f2b(acc[r][0] * inv);
    st.y = f2b(acc[r][1] * inv);
    *(ushort2*)(op + (size_t)((ty << 2) + r) * 256 + (tx << 1)) = st;
  }
}

// ---------------- reference points: sigmoid(q2 @ ref_w^T + ref_b), bf16 q ----------------
__global__ __launch_bounds__(256) void ref_kernel(
    const ushort* __restrict__ q2, const float* __restrict__ rw,
    const float* __restrict__ rb, float* __restrict__ refo) {
  int lane = threadIdx.x & 63;
  int row = (blockIdx.x << 2) + (threadIdx.x >> 6);
  ushort4 xr = ((const ushort4*)(q2 + (size_t)row * 256))[lane];
  float x0 = b2f(xr.x), x1 = b2f(xr.y), x2 = b2f(xr.z), x3 = b2f(xr.w);
  float4 w0 = ((const float4*)rw)[lane];
  float4 w1 = ((const float4*)(rw + 256))[lane];
  float d0 = x0 * w0.x + x1 * w0.y + x2 * w0.z + x3 * w0.w;
  float d1 = x0 * w1.x + x1 * w1.y + x2 * w1.z + x3 * w1.w;
#pragma unroll
  for (int off = 32; off; off >>= 1) {
    d0 += __shfl_xor(d0, off);
    d1 += __shfl_xor(d1, off);
  }
  if (lane == 0) {
    refo[row * 2 + 0] = 1.0f / (1.0f + __expf(-(d0 + rb[0])));
    refo[row * 2 + 1] = 1.0f / (1.0f + __expf(-(d1 + rb[1])));
  }
}

// ---------------- aw softmax: one thread per (q,h), in-place over 24 values ----------
__global__ __launch_bounds__(256) void aw_softmax_kernel(float* __restrict__ aw) {
  int i = blockIdx.x * 256 + threadIdx.x;  // (q*8 + h), 65536 total
  float* a = aw + (size_t)(i >> 3) * 192 + (i & 7) * 24;
  float v[24];
  float m = -1e30f;
#pragma unroll
  for (int k = 0; k < 24; k++) {
    v[k] = a[k];
    m = fmaxf(m, v[k]);
  }
  float sm = 0.f;
#pragma unroll
  for (int k = 0; k < 24; k++) {
    v[k] = __expf(v[k] - m);
    sm += v[k];
  }
  float inv = 1.0f / sm;
#pragma unroll
  for (int k = 0; k < 24; k++) a[k] = v[k] * inv;
}

// ---------------- msdeform gather: block=query(192 thr), thread=(h,level,dg4) ----------
// 8 points x 4 corners = 32 ushort4 gathers per thread; fp32 per-level partial out.
__global__ __launch_bounds__(192) void msdeform_gather(
    const ushort* __restrict__ value, const float* __restrict__ ref,
    const float* __restrict__ off, const float* __restrict__ aw_n,
    float* __restrict__ lvl) {
  int q = blockIdx.x;
  int b = q >> 10;
  __shared__ float s_off[384];
  __shared__ float s_aw[192];
  int t = threadIdx.x;
#pragma unroll
  for (int i = 0; i < 3; i++) {
    int j = t + 192 * i;
    if (j < 384)
      s_off[j] = off[(size_t)q * 384 + j];
    else
      s_aw[j - 384] = aw_n[(size_t)q * 192 + (j - 384)];
  }
  __syncthreads();
  int h = t / 24;
  int rem = t - h * 24;
  int l = rem >> 3;
  int dg = rem & 7;
  int dim = (l == 0) ? 128 : ((l == 1) ? 64 : 32);
  int start = (l == 0) ? 0 : ((l == 1) ? 16384 : 20480);
  float fdim = (float)dim;
  float rx = ref[q * 2 + 0] * fdim - 0.5f;
  float ry = ref[q * 2 + 1] * fdim - 0.5f;
  const ushort* vl = value + ((size_t)b * SROWS + start) * 256 + h * 32 + dg * 4;
  int ebase = h * 24 + l * 8;
  float a0 = 0.f, a1 = 0.f, a2 = 0.f, a3 = 0.f;
#pragma unroll 2
  for (int p = 0; p < 8; p++) {
    int e = ebase + p;
    float gx = rx + s_off[e * 2];
    float gy = ry + s_off[e * 2 + 1];
    float fx = floorf(gx), fy = floorf(gy);
    int x0 = (int)fx, y0 = (int)fy;
    float lx = gx - fx, ly = gy - fy;
    float w = s_aw[e];
    bool xin0 = (x0 >= 0) & (x0 < dim);
    bool xin1 = (x0 + 1 >= 0) & (x0 + 1 < dim);
    bool yin0 = (y0 >= 0) & (y0 < dim);
    bool yin1 = (y0 + 1 >= 0) & (y0 + 1 < dim);
    ushort4 u00 = {0, 0, 0, 0}, u01 = {0, 0, 0, 0}, u10 = {0, 0, 0, 0}, u11 = {0, 0, 0, 0};
    if (yin0 && xin0) u00 = *(const ushort4*)(vl + (size_t)(y0 * dim + x0) * 256);
    if (yin0 && xin1) u01 = *(const ushort4*)(vl + (size_t)(y0 * dim + x0 + 1) * 256);
    if (yin1 && xin0) u10 = *(const ushort4*)(vl + (size_t)((y0 + 1) * dim + x0) * 256);
    if (yin1 && xin1) u11 = *(const ushort4*)(vl + (size_t)((y0 + 1) * dim + x0 + 1) * 256);
    float w00 = w * (1.f - lx) * (1.f - ly);
    float w01 = w * lx * (1.f - ly);
    float w10 = w * (1.f - lx) * ly;
    float w11 = w * lx * ly;
    a0 += b2f(u00.x) * w00 + b2f(u01.x) * w01 + b2f(u10.x) * w10 + b2f(u11.x) * w11;
    a1 += b2f(u00.y) * w00 + b2f(u01.y) * w01 + b2f(u10.y) * w10 + b2f(u11.y) * w11;
    a2 += b2f(u00.z) * w00 + b2f(u01.z) * w01 + b2f(u10.z) * w10 + b2f(u11.z) * w11;
    a3 += b2f(u00.w) * w00 + b2f(u01.w) * w01 + b2f(u10.w) * w10 + b2f(u11.w) * w11;
  }
  float4 o = make_float4(a0, a1, a2, a3);
  *(float4*)&lvl[(((size_t)q * 8 + h) * 3 + l) * 32 + dg * 4] = o;
}

// ---------------- msdeform reduce: sum 3 levels, bf16 out ----------------
__global__ __launch_bounds__(256) void msdeform_reduce(
    const float* __restrict__ lvl, ushort* __restrict__ out) {
  int t = threadIdx.x;
  int q = (blockIdx.x << 2) + (t >> 6);
  int h = (t >> 3) & 7, dg = t & 7;
  const float* p = lvl + ((size_t)q * 8 + h) * 96 + dg * 4;
  float4 x = *(const float4*)p;
  float4 y = *(const float4*)(p + 32);
  float4 z = *(const float4*)(p + 64);
  ushort4 o;
  o.x = f2b(x.x + y.x + z.x);
  o.y = f2b(x.y + y.y + z.y);
  o.z = f2b(x.z + y.z + z.z);
  o.w = f2b(x.w + y.w + z.w);
  *(ushort4*)(out + (size_t)q * 256 + h * 32 + dg * 4) = o;
}

extern "C" void kernel_launch(void* const* d_in, const int* in_sizes, int n_in,
                              void* d_out, int out_size, void* d_ws, size_t ws_size,
                              hipStream_t stream) {
  const float* tgt = (const float*)d_in[0];
  const float* memory = (const float*)d_in[1];
  const float* n1_w = (const float*)d_in[2];
  const float* n1_b = (const float*)d_in[3];
  const float* attn_in_w = (const float*)d_in[4];
  const float* attn_in_b = (const float*)d_in[5];
  const float* attn_out_w = (const float*)d_in[6];
  const float* attn_out_b = (const float*)d_in[7];
  const float* n2_w = (const float*)d_in[8];
  const float* n2_b = (const float*)d_in[9];
  const float* ref_w = (const float*)d_in[10];
  const float* ref_b = (const float*)d_in[11];
  const float* so_w = (const float*)d_in[12];
  const float* so_b = (const float*)d_in[13];
  const float* aw_w = (const float*)d_in[14];
  const float* aw_b = (const float*)d_in[15];
  const float* vp_w = (const float*)d_in[16];
  const float* vp_b = (const float*)d_in[17];
  const float* op_w = (const float*)d_in[18];
  const float* op_b = (const float*)d_in[19];
  const float* n3_w = (const float*)d_in[20];
  const float* n3_b = (const float*)d_in[21];
  const float* l1_w = (const float*)d_in[22];
  const float* l1_b = (const float*)d_in[23];
  const float* l2_w = (const float*)d_in[24];
  const float* l2_b = (const float*)d_in[25];
  float* out = (float*)d_out;

  // workspace layout (bytes)
  char* base = (char*)d_ws;
  float* bufQKV = (float*)base;                    // 25,165,824 (fp32 qkv; union w/ lvl_buf, ff1_bf)
  float* off_buf = (float*)(base + 25165824);      // 12,582,912
  float* aw_buf = (float*)(base + 37748736);       //  6,291,456
  float* ref_buf = (float*)(base + 44040192);      //     65,536
  ushort* q_bf = (ushort*)(base + 44105728);       //  4,194,304
  ushort* mha_bf = (ushort*)(base + 48300032);     //  4,194,304
  ushort* samp_bf = (ushort*)(base + 52494336);    //  4,194,304
  ushort* mem_bf = (ushort*)(base + 56688640);     // 88,080,384
  ushort* val_bf = (ushort*)(base + 144769024);    // 88,080,384
  ushort* wts = (ushort*)(base + 232849408);       //  2,129,920  -> total ~235 MB
  ushort* ff1_bf = (ushort*)bufQKV;                // union: FFN phase only
  float* lvl_buf = (float*)bufQKV;                 // union: msdeform phase only (25,165,824 B exactly)

  ushort* w_attn_in = wts;               // 196608
  ushort* w_attn_out = wts + 196608;     // 65536
  ushort* w_so = wts + 262144;           // 98304
  ushort* w_aw = wts + 360448;           // 49152
  ushort* w_vp = wts + 409600;           // 65536
  ushort* w_op = wts + 475136;           // 65536
  ushort* w_l1 = wts + 540672;           // 262144
  ushort* w_l2 = wts + 802816;           // 262144

  const int NR = 8192;

  // ---- pre-convert weights + memory to bf16 ----
  f2bf_kernel<<<21504, 256, 0, stream>>>(memory, mem_bf);
  f2bf_kernel<<<96, 256, 0, stream>>>(attn_in_w, w_attn_in);
  f2bf_kernel<<<32, 256, 0, stream>>>(attn_out_w, w_attn_out);
  f2bf_kernel<<<48, 256, 0, stream>>>(so_w, w_so);
  f2bf_kernel<<<24, 256, 0, stream>>>(aw_w, w_aw);
  f2bf_kernel<<<32, 256, 0, stream>>>(vp_w, w_vp);
  f2bf_kernel<<<32, 256, 0, stream>>>(op_w, w_op);
  f2bf_kernel<<<128, 256, 0, stream>>>(l1_w, w_l1);
  f2bf_kernel<<<128, 256, 0, stream>>>(l2_w, w_l2);

  // ---- self-attention block ----
  ln_kernel<<<NR / 4, 256, 0, stream>>>(tgt, n1_w, n1_b, q_bf);
  gemm_bf16<false, false, false><<<dim3(NR / 128, 768 / 64), 256, 0, stream>>>(
      (const short*)q_bf, (const short*)w_attn_in, attn_in_b, nullptr, bufQKV, NR, 768, 256);
  attn_tiled<<<dim3(16, 64), 256, 0, stream>>>(bufQKV, mha_bf);
  gemm_bf16<false, true, false><<<dim3(NR / 128, 256 / 64), 256, 0, stream>>>(
      (const short*)mha_bf, (const short*)w_attn_out, attn_out_b, tgt, out, NR, 256, 256);

  // ---- deformable cross-attention block ----
  ln_kernel<<<NR / 4, 256, 0, stream>>>(out, n2_w, n2_b, q_bf);
  gemm_bf16<false, false, true><<<dim3(8 * SROWS / 128, 256 / 64), 256, 0, stream>>>(
      (const short*)mem_bf, (const short*)w_vp, vp_b, nullptr, val_bf, 8 * SROWS, 256, 256);
  ref_kernel<<<NR / 4, 256, 0, stream>>>(q_bf, ref_w, ref_b, ref_buf);
  gemm_bf16<false, false, false><<<dim3(NR / 128, 384 / 64), 256, 0, stream>>>(
      (const short*)q_bf, (const short*)w_so, so_b, nullptr, off_buf, NR, 384, 256);
  gemm_bf16<false, false, false><<<dim3(NR / 128, 192 / 64), 256, 0, stream>>>(
      (const short*)q_bf, (const short*)w_aw, aw_b, nullptr, aw_buf, NR, 192, 256);
  aw_softmax_kernel<<<256, 256, 0, stream>>>(aw_buf);
  msdeform_gather<<<NR, 192, 0, stream>>>(val_bf, ref_buf, off_buf, aw_buf, lvl_buf);
  msdeform_reduce<<<NR / 4, 256, 0, stream>>>(lvl_buf, samp_bf);
  gemm_bf16<false, true, false><<<dim3(NR / 128, 256 / 64), 256, 0, stream>>>(
      (const short*)samp_bf, (const short*)w_op, op_b, out, out, NR, 256, 256);

  // ---- FFN block ----
  ln_kernel<<<NR / 4, 256, 0, stream>>>(out, n3_w, n3_b, q_bf);
  gemm_bf16<true, false, true><<<dim3(NR / 128, 1024 / 64), 256, 0, stream>>>(
      (const short*)q_bf, (const short*)w_l1, l1_b, nullptr, ff1_bf, NR, 1024, 256);
  gemm_bf16<false, true, false><<<dim3(NR / 128, 256 / 64), 256, 0, stream>>>(
      (const short*)ff1_bf, (const short*)w_l2, l2_b, out, out, NR, 256, 1024);
}

// Round 7
// 589.791 us; speedup vs baseline: 4.7997x; 1.2425x over previous
//
#include <hip/hip_runtime.h>
#include <math.h>

#define NQR 1024
#define CDIM 256
#define SROWS 21504
#define ATTN_SCALE 0.17677669529663687f

typedef __attribute__((ext_vector_type(8))) short bf16x8;
typedef __attribute__((ext_vector_type(4))) float f32x4;

__device__ __forceinline__ ushort f2b(float x) {  // fp32 -> bf16 bits, RNE
  unsigned u = __float_as_uint(x);
  u += 0x7FFFu + ((u >> 16) & 1u);
  return (ushort)(u >> 16);
}
__device__ __forceinline__ float b2f(ushort b) {
  return __uint_as_float(((unsigned)b) << 16);
}

// ---------------- fp32 -> bf16 elementwise convert (n multiple of 2048) ----------------
__global__ __launch_bounds__(256) void f2bf_kernel(
    const float* __restrict__ x, ushort* __restrict__ y) {
  int i = blockIdx.x * 256 + threadIdx.x;  // each thread: 8 elements
  float4 v0 = ((const float4*)x)[i * 2];
  float4 v1 = ((const float4*)x)[i * 2 + 1];
  ushort4 o0, o1;
  o0.x = f2b(v0.x); o0.y = f2b(v0.y); o0.z = f2b(v0.z); o0.w = f2b(v0.w);
  o1.x = f2b(v1.x); o1.y = f2b(v1.y); o1.z = f2b(v1.z); o1.w = f2b(v1.w);
  ((ushort4*)y)[i * 2] = o0;
  ((ushort4*)y)[i * 2 + 1] = o1;
}

// ---------------- LayerNorm: one wave per 256-wide row, bf16 out ----------------
__global__ __launch_bounds__(256) void ln_kernel(
    const float* __restrict__ x, const float* __restrict__ w,
    const float* __restrict__ b, ushort* __restrict__ y) {
  int lane = threadIdx.x & 63;
  int row = (blockIdx.x << 2) + (threadIdx.x >> 6);
  float4 v = ((const float4*)(x + (size_t)row * CDIM))[lane];
  float s = v.x + v.y + v.z + v.w;
  float ss = v.x * v.x + v.y * v.y + v.z * v.z + v.w * v.w;
#pragma unroll
  for (int off = 32; off; off >>= 1) {
    s += __shfl_xor(s, off);
    ss += __shfl_xor(ss, off);
  }
  float m = s * (1.0f / 256.0f);
  float var = ss * (1.0f / 256.0f) - m * m;
  float r = rsqrtf(var + 1e-5f);
  float4 wv = ((const float4*)w)[lane];
  float4 bv = ((const float4*)b)[lane];
  ushort4 o;
  o.x = f2b((v.x - m) * r * wv.x + bv.x);
  o.y = f2b((v.y - m) * r * wv.y + bv.y);
  o.z = f2b((v.z - m) * r * wv.z + bv.z);
  o.w = f2b((v.w - m) * r * wv.w + bv.w);
  ((ushort4*)(y + (size_t)row * CDIM))[lane] = o;
}

// ---------------- bf16 MFMA GEMM: C[M,N] = A[M,K] @ W[N,K]^T + bias (+gelu, +res) ----
template <bool GELU, bool RES, bool OUTBF>
__global__ __launch_bounds__(256) void gemm_bf16(
    const short* __restrict__ A, const short* __restrict__ W,
    const float* __restrict__ bias, const float* __restrict__ res,
    void* __restrict__ Cout, int M, int N, int K) {
  __shared__ short As[128 * 72];
  __shared__ short Bs[64 * 72];
  int t = threadIdx.x;
  int l = t & 63;
  int wave = t >> 6;
  int wm = wave >> 1, wn = wave & 1;
  int lrow = t >> 3;        // 0..31
  int lcol = (t & 7) << 3;  // 0..56
  size_t m0 = (size_t)blockIdx.x * 128;
  int n0 = blockIdx.y * 64;
  const short* Ag = A + (m0 + lrow) * K + lcol;
  const short* Wg = W + (size_t)(n0 + lrow) * K + lcol;
  f32x4 acc[4][2] = {};
  int fr = l & 15, fq = l >> 4;
  for (int k0 = 0; k0 < K; k0 += 64) {
    uint4 a0 = *(const uint4*)(Ag + k0);
    uint4 a1 = *(const uint4*)(Ag + (size_t)32 * K + k0);
    uint4 a2 = *(const uint4*)(Ag + (size_t)64 * K + k0);
    uint4 a3 = *(const uint4*)(Ag + (size_t)96 * K + k0);
    uint4 b0 = *(const uint4*)(Wg + k0);
    uint4 b1 = *(const uint4*)(Wg + (size_t)32 * K + k0);
    __syncthreads();
    *(uint4*)&As[lrow * 72 + lcol] = a0;
    *(uint4*)&As[(lrow + 32) * 72 + lcol] = a1;
    *(uint4*)&As[(lrow + 64) * 72 + lcol] = a2;
    *(uint4*)&As[(lrow + 96) * 72 + lcol] = a3;
    *(uint4*)&Bs[lrow * 72 + lcol] = b0;
    *(uint4*)&Bs[(lrow + 32) * 72 + lcol] = b1;
    __syncthreads();
#pragma unroll
    for (int kk = 0; kk < 2; kk++) {
      int kb = kk * 32 + fq * 8;
      bf16x8 af[4], bfr[2];
#pragma unroll
      for (int mi = 0; mi < 4; mi++)
        af[mi] = *(const bf16x8*)&As[(wm * 64 + mi * 16 + fr) * 72 + kb];
#pragma unroll
      for (int ni = 0; ni < 2; ni++)
        bfr[ni] = *(const bf16x8*)&Bs[(wn * 32 + ni * 16 + fr) * 72 + kb];
#pragma unroll
      for (int mi = 0; mi < 4; mi++)
#pragma unroll
        for (int ni = 0; ni < 2; ni++)
          acc[mi][ni] = __builtin_amdgcn_mfma_f32_16x16x32_bf16(
              af[mi], bfr[ni], acc[mi][ni], 0, 0, 0);
    }
  }
#pragma unroll
  for (int ni = 0; ni < 2; ni++) {
    int gcol = n0 + wn * 32 + ni * 16 + fr;
    float bv = bias[gcol];
#pragma unroll
    for (int mi = 0; mi < 4; mi++) {
#pragma unroll
      for (int j = 0; j < 4; j++) {
        size_t grow = m0 + wm * 64 + mi * 16 + fq * 4 + j;
        float v = acc[mi][ni][j] + bv;
        if (GELU) v = 0.5f * v * (1.0f + erff(v * 0.70710678118654752f));
        if (RES) v += res[grow * N + gcol];
        if (OUTBF)
          ((ushort*)Cout)[grow * N + gcol] = f2b(v);
        else
          ((float*)Cout)[grow * N + gcol] = v;
      }
    }
  }
}

// ---------------- MFMA flash MHA: bf16 qkv in, bf16 out ----------------
// Block = (b,h,q-tile 64). 4 waves x 16 q-rows. K-tiles of 64.
// Kt[64][40]: frag reads 2-way free. Vt[32][72] transposed via k-pair b32 packs
// (writes conflict-free, frag reads 2-way free). P via LDS bf16 per wave.
__global__ __launch_bounds__(256) void attn_mfma(
    const ushort* __restrict__ qkv, ushort* __restrict__ o) {
  __shared__ ushort Kt[64][40];
  __shared__ ushort Vt[32][72];
  __shared__ ushort Ps[4][16][72];
  int qt = blockIdx.x, bh = blockIdx.y;
  int b = bh >> 3, h = bh & 7;
  int t = threadIdx.x;
  int w = t >> 6, l = t & 63;
  int fr = l & 15, fg = l >> 4;

  // Q fragment (A): row=fr, k=fg*8+j over D=32
  const ushort* qp =
      qkv + ((size_t)(b * NQR + qt * 64 + w * 16 + fr)) * 768 + h * 32 + fg * 8;
  bf16x8 qf = *(const bf16x8*)qp;

  float mrow[4] = {-1e30f, -1e30f, -1e30f, -1e30f};
  float lsum[4] = {0.f, 0.f, 0.f, 0.f};
  f32x4 accO[2] = {};

  // staging roles
  int rp = t & 31, vc = (t >> 5) & 3;          // threads 0..127: V k-pair rp, d-chunk vc
  int tt = t & 127;
  int krow = tt >> 1, kh = (tt & 1) * 16;      // threads 128..255: K row, half-row

  const ushort* kvbase = qkv + (size_t)b * NQR * 768 + 256 + h * 32;

  for (int kt = 0; kt < 16; kt++) {
    int k0 = kt * 64;
    uint4 ld0, ld1;
    if (t < 128) {
      const ushort* vp = kvbase + 256 + (size_t)(k0 + 2 * rp) * 768 + vc * 8;
      ld0 = *(const uint4*)vp;
      ld1 = *(const uint4*)(vp + 768);
    } else {
      const ushort* kp = kvbase + (size_t)(k0 + krow) * 768 + kh;
      ld0 = *(const uint4*)kp;
      ld1 = *(const uint4*)(kp + 8);
    }
    __syncthreads();
    if (t < 128) {
      ushort va[8], vb[8];
      *(uint4*)va = ld0;
      *(uint4*)vb = ld1;
#pragma unroll
      for (int j = 0; j < 8; j++) {
        unsigned pack = (unsigned)va[j] | ((unsigned)vb[j] << 16);
        *(unsigned*)&Vt[vc * 8 + j][2 * rp] = pack;
      }
    } else {
      *(uint4*)&Kt[krow][kh] = ld0;
      *(uint4*)&Kt[krow][kh + 8] = ld1;
    }
    __syncthreads();
    // QK^T: S[q=fg*4+j][k=nt*16+fr] per lane
    f32x4 sf[4];
#pragma unroll
    for (int nt = 0; nt < 4; nt++) {
      bf16x8 kf = *(const bf16x8*)&Kt[nt * 16 + fr][fg * 8];
      f32x4 z = {0.f, 0.f, 0.f, 0.f};
      sf[nt] = __builtin_amdgcn_mfma_f32_16x16x32_bf16(qf, kf, z, 0, 0, 0);
    }
    // online softmax per q-row (16-lane group reduce)
#pragma unroll
    for (int j = 0; j < 4; j++) {
      float s0 = sf[0][j] * ATTN_SCALE;
      float s1 = sf[1][j] * ATTN_SCALE;
      float s2 = sf[2][j] * ATTN_SCALE;
      float s3 = sf[3][j] * ATTN_SCALE;
      float mt = fmaxf(fmaxf(s0, s1), fmaxf(s2, s3));
      mt = fmaxf(mt, __shfl_xor(mt, 1));
      mt = fmaxf(mt, __shfl_xor(mt, 2));
      mt = fmaxf(mt, __shfl_xor(mt, 4));
      mt = fmaxf(mt, __shfl_xor(mt, 8));
      float mn = fmaxf(mrow[j], mt);
      float scl = __expf(mrow[j] - mn);
      mrow[j] = mn;
      float p0 = __expf(s0 - mn), p1 = __expf(s1 - mn);
      float p2 = __expf(s2 - mn), p3 = __expf(s3 - mn);
      float rs = p0 + p1 + p2 + p3;
      rs += __shfl_xor(rs, 1);
      rs += __shfl_xor(rs, 2);
      rs += __shfl_xor(rs, 4);
      rs += __shfl_xor(rs, 8);
      lsum[j] = lsum[j] * scl + rs;
      accO[0][j] *= scl;
      accO[1][j] *= scl;
      int lq = fg * 4 + j;
      Ps[w][lq][fr] = f2b(p0);
      Ps[w][lq][16 + fr] = f2b(p1);
      Ps[w][lq][32 + fr] = f2b(p2);
      Ps[w][lq][48 + fr] = f2b(p3);
    }
    // PV: O[q][d] += P[q][k] V[k][d]
#pragma unroll
    for (int kk = 0; kk < 2; kk++) {
      bf16x8 pf = *(const bf16x8*)&Ps[w][fr][kk * 32 + fg * 8];
#pragma unroll
      for (int nt = 0; nt < 2; nt++) {
        bf16x8 vf = *(const bf16x8*)&Vt[nt * 16 + fr][kk * 32 + fg * 8];
        accO[nt] = __builtin_amdgcn_mfma_f32_16x16x32_bf16(pf, vf, accO[nt], 0, 0, 0);
      }
    }
  }
  ushort* op = o + ((size_t)(b * NQR + qt * 64 + w * 16)) * 256 + h * 32;
#pragma unroll
  for (int j = 0; j < 4; j++) {
    float inv = 1.0f / lsum[j];
    int lq = fg * 4 + j;
#pragma unroll
    for (int nt = 0; nt < 2; nt++)
      op[(size_t)lq * 256 + nt * 16 + fr] = f2b(accO[nt][j] * inv);
  }
}

// ---------------- reference points: sigmoid(q2 @ ref_w^T + ref_b), bf16 q ----------------
__global__ __launch_bounds__(256) void ref_kernel(
    const ushort* __restrict__ q2, const float* __restrict__ rw,
    const float* __restrict__ rb, float* __restrict__ refo) {
  int lane = threadIdx.x & 63;
  int row = (blockIdx.x << 2) + (threadIdx.x >> 6);
  ushort4 xr = ((const ushort4*)(q2 + (size_t)row * 256))[lane];
  float x0 = b2f(xr.x), x1 = b2f(xr.y), x2 = b2f(xr.z), x3 = b2f(xr.w);
  float4 w0 = ((const float4*)rw)[lane];
  float4 w1 = ((const float4*)(rw + 256))[lane];
  float d0 = x0 * w0.x + x1 * w0.y + x2 * w0.z + x3 * w0.w;
  float d1 = x0 * w1.x + x1 * w1.y + x2 * w1.z + x3 * w1.w;
#pragma unroll
  for (int off = 32; off; off >>= 1) {
    d0 += __shfl_xor(d0, off);
    d1 += __shfl_xor(d1, off);
  }
  if (lane == 0) {
    refo[row * 2 + 0] = 1.0f / (1.0f + __expf(-(d0 + rb[0])));
    refo[row * 2 + 1] = 1.0f / (1.0f + __expf(-(d1 + rb[1])));
  }
}

// ---------------- aw softmax: one thread per (q,h), in-place over 24 values ----------
__global__ __launch_bounds__(256) void aw_softmax_kernel(float* __restrict__ aw) {
  int i = blockIdx.x * 256 + threadIdx.x;  // (q*8 + h), 65536 total
  float* a = aw + (size_t)(i >> 3) * 192 + (i & 7) * 24;
  float v[24];
  float m = -1e30f;
#pragma unroll
  for (int k = 0; k < 24; k++) {
    v[k] = a[k];
    m = fmaxf(m, v[k]);
  }
  float sm = 0.f;
#pragma unroll
  for (int k = 0; k < 24; k++) {
    v[k] = __expf(v[k] - m);
    sm += v[k];
  }
  float inv = 1.0f / sm;
#pragma unroll
  for (int k = 0; k < 24; k++) a[k] = v[k] * inv;
}

// ---------------- msdeform gather: block=query(192 thr), thread=(h,level,dg4) ----------
__global__ __launch_bounds__(192) void msdeform_gather(
    const ushort* __restrict__ value, const float* __restrict__ ref,
    const float* __restrict__ off, const float* __restrict__ aw_n,
    float* __restrict__ lvl) {
  int q = blockIdx.x;
  int b = q >> 10;
  __shared__ float s_off[384];
  __shared__ float s_aw[192];
  int t = threadIdx.x;
#pragma unroll
  for (int i = 0; i < 3; i++) {
    int j = t + 192 * i;
    if (j < 384)
      s_off[j] = off[(size_t)q * 384 + j];
    else
      s_aw[j - 384] = aw_n[(size_t)q * 192 + (j - 384)];
  }
  __syncthreads();
  int h = t / 24;
  int rem = t - h * 24;
  int l = rem >> 3;
  int dg = rem & 7;
  int dim = (l == 0) ? 128 : ((l == 1) ? 64 : 32);
  int start = (l == 0) ? 0 : ((l == 1) ? 16384 : 20480);
  float fdim = (float)dim;
  float rx = ref[q * 2 + 0] * fdim - 0.5f;
  float ry = ref[q * 2 + 1] * fdim - 0.5f;
  const ushort* vl = value + ((size_t)b * SROWS + start) * 256 + h * 32 + dg * 4;
  int ebase = h * 24 + l * 8;
  float a0 = 0.f, a1 = 0.f, a2 = 0.f, a3 = 0.f;
#pragma unroll 2
  for (int p = 0; p < 8; p++) {
    int e = ebase + p;
    float gx = rx + s_off[e * 2];
    float gy = ry + s_off[e * 2 + 1];
    float fx = floorf(gx), fy = floorf(gy);
    int x0 = (int)fx, y0 = (int)fy;
    float lx = gx - fx, ly = gy - fy;
    float w = s_aw[e];
    bool xin0 = (x0 >= 0) & (x0 < dim);
    bool xin1 = (x0 + 1 >= 0) & (x0 + 1 < dim);
    bool yin0 = (y0 >= 0) & (y0 < dim);
    bool yin1 = (y0 + 1 >= 0) & (y0 + 1 < dim);
    ushort4 u00 = {0, 0, 0, 0}, u01 = {0, 0, 0, 0}, u10 = {0, 0, 0, 0}, u11 = {0, 0, 0, 0};
    if (yin0 && xin0) u00 = *(const ushort4*)(vl + (size_t)(y0 * dim + x0) * 256);
    if (yin0 && xin1) u01 = *(const ushort4*)(vl + (size_t)(y0 * dim + x0 + 1) * 256);
    if (yin1 && xin0) u10 = *(const ushort4*)(vl + (size_t)((y0 + 1) * dim + x0) * 256);
    if (yin1 && xin1) u11 = *(const ushort4*)(vl + (size_t)((y0 + 1) * dim + x0 + 1) * 256);
    float w00 = w * (1.f - lx) * (1.f - ly);
    float w01 = w * lx * (1.f - ly);
    float w10 = w * (1.f - lx) * ly;
    float w11 = w * lx * ly;
    a0 += b2f(u00.x) * w00 + b2f(u01.x) * w01 + b2f(u10.x) * w10 + b2f(u11.x) * w11;
    a1 += b2f(u00.y) * w00 + b2f(u01.y) * w01 + b2f(u10.y) * w10 + b2f(u11.y) * w11;
    a2 += b2f(u00.z) * w00 + b2f(u01.z) * w01 + b2f(u10.z) * w10 + b2f(u11.z) * w11;
    a3 += b2f(u00.w) * w00 + b2f(u01.w) * w01 + b2f(u10.w) * w10 + b2f(u11.w) * w11;
  }
  float4 o = make_float4(a0, a1, a2, a3);
  *(float4*)&lvl[(((size_t)q * 8 + h) * 3 + l) * 32 + dg * 4] = o;
}

// ---------------- msdeform reduce: sum 3 levels, bf16 out ----------------
__global__ __launch_bounds__(256) void msdeform_reduce(
    const float* __restrict__ lvl, ushort* __restrict__ out) {
  int t = threadIdx.x;
  int q = (blockIdx.x << 2) + (t >> 6);
  int h = (t >> 3) & 7, dg = t & 7;
  const float* p = lvl + ((size_t)q * 8 + h) * 96 + dg * 4;
  float4 x = *(const float4*)p;
  float4 y = *(const float4*)(p + 32);
  float4 z = *(const float4*)(p + 64);
  ushort4 o;
  o.x = f2b(x.x + y.x + z.x);
  o.y = f2b(x.y + y.y + z.y);
  o.z = f2b(x.z + y.z + z.z);
  o.w = f2b(x.w + y.w + z.w);
  *(ushort4*)(out + (size_t)q * 256 + h * 32 + dg * 4) = o;
}

extern "C" void kernel_launch(void* const* d_in, const int* in_sizes, int n_in,
                              void* d_out, int out_size, void* d_ws, size_t ws_size,
                              hipStream_t stream) {
  const float* tgt = (const float*)d_in[0];
  const float* memory = (const float*)d_in[1];
  const float* n1_w = (const float*)d_in[2];
  const float* n1_b = (const float*)d_in[3];
  const float* attn_in_w = (const float*)d_in[4];
  const float* attn_in_b = (const float*)d_in[5];
  const float* attn_out_w = (const float*)d_in[6];
  const float* attn_out_b = (const float*)d_in[7];
  const float* n2_w = (const float*)d_in[8];
  const float* n2_b = (const float*)d_in[9];
  const float* ref_w = (const float*)d_in[10];
  const float* ref_b = (const float*)d_in[11];
  const float* so_w = (const float*)d_in[12];
  const float* so_b = (const float*)d_in[13];
  const float* aw_w = (const float*)d_in[14];
  const float* aw_b = (const float*)d_in[15];
  const float* vp_w = (const float*)d_in[16];
  const float* vp_b = (const float*)d_in[17];
  const float* op_w = (const float*)d_in[18];
  const float* op_b = (const float*)d_in[19];
  const float* n3_w = (const float*)d_in[20];
  const float* n3_b = (const float*)d_in[21];
  const float* l1_w = (const float*)d_in[22];
  const float* l1_b = (const float*)d_in[23];
  const float* l2_w = (const float*)d_in[24];
  const float* l2_b = (const float*)d_in[25];
  float* out = (float*)d_out;

  // workspace layout (bytes)
  char* base = (char*)d_ws;
  ushort* qkv_bf = (ushort*)base;                  // 12,582,912 (bf16 qkv; union w/ lvl_buf, ff1_bf)
  float* off_buf = (float*)(base + 25165824);      // 12,582,912
  float* aw_buf = (float*)(base + 37748736);       //  6,291,456
  float* ref_buf = (float*)(base + 44040192);      //     65,536
  ushort* q_bf = (ushort*)(base + 44105728);       //  4,194,304
  ushort* mha_bf = (ushort*)(base + 48300032);     //  4,194,304
  ushort* samp_bf = (ushort*)(base + 52494336);    //  4,194,304
  ushort* mem_bf = (ushort*)(base + 56688640);     // 88,080,384
  ushort* val_bf = (ushort*)(base + 144769024);    // 88,080,384
  ushort* wts = (ushort*)(base + 232849408);       //  2,129,920  -> total ~235 MB
  ushort* ff1_bf = (ushort*)base;                  // union: FFN phase only
  float* lvl_buf = (float*)base;                   // union: msdeform phase only (25,165,824 B)

  ushort* w_attn_in = wts;               // 196608
  ushort* w_attn_out = wts + 196608;     // 65536
  ushort* w_so = wts + 262144;           // 98304
  ushort* w_aw = wts + 360448;           // 49152
  ushort* w_vp = wts + 409600;           // 65536
  ushort* w_op = wts + 475136;           // 65536
  ushort* w_l1 = wts + 540672;           // 262144
  ushort* w_l2 = wts + 802816;           // 262144

  const int NR = 8192;

  // ---- pre-convert weights + memory to bf16 ----
  f2bf_kernel<<<21504, 256, 0, stream>>>(memory, mem_bf);
  f2bf_kernel<<<96, 256, 0, stream>>>(attn_in_w, w_attn_in);
  f2bf_kernel<<<32, 256, 0, stream>>>(attn_out_w, w_attn_out);
  f2bf_kernel<<<48, 256, 0, stream>>>(so_w, w_so);
  f2bf_kernel<<<24, 256, 0, stream>>>(aw_w, w_aw);
  f2bf_kernel<<<32, 256, 0, stream>>>(vp_w, w_vp);
  f2bf_kernel<<<32, 256, 0, stream>>>(op_w, w_op);
  f2bf_kernel<<<128, 256, 0, stream>>>(l1_w, w_l1);
  f2bf_kernel<<<128, 256, 0, stream>>>(l2_w, w_l2);

  // ---- self-attention block ----
  ln_kernel<<<NR / 4, 256, 0, stream>>>(tgt, n1_w, n1_b, q_bf);
  gemm_bf16<false, false, true><<<dim3(NR / 128, 768 / 64), 256, 0, stream>>>(
      (const short*)q_bf, (const short*)w_attn_in, attn_in_b, nullptr, qkv_bf, NR, 768, 256);
  attn_mfma<<<dim3(16, 64), 256, 0, stream>>>(qkv_bf, mha_bf);
  gemm_bf16<false, true, false><<<dim3(NR / 128, 256 / 64), 256, 0, stream>>>(
      (const short*)mha_bf, (const short*)w_attn_out, attn_out_b, tgt, out, NR, 256, 256);

  // ---- deformable cross-attention block ----
  ln_kernel<<<NR / 4, 256, 0, stream>>>(out, n2_w, n2_b, q_bf);
  gemm_bf16<false, false, true><<<dim3(8 * SROWS / 128, 256 / 64), 256, 0, stream>>>(
      (const short*)mem_bf, (const short*)w_vp, vp_b, nullptr, val_bf, 8 * SROWS, 256, 256);
  ref_kernel<<<NR / 4, 256, 0, stream>>>(q_bf, ref_w, ref_b, ref_buf);
  gemm_bf16<false, false, false><<<dim3(NR / 128, 384 / 64), 256, 0, stream>>>(
      (const short*)q_bf, (const short*)w_so, so_b, nullptr, off_buf, NR, 384, 256);
  gemm_bf16<false, false, false><<<dim3(NR / 128, 192 / 64), 256, 0, stream>>>(
      (const short*)q_bf, (const short*)w_aw, aw_b, nullptr, aw_buf, NR, 192, 256);
  aw_softmax_kernel<<<256, 256, 0, stream>>>(aw_buf);
  msdeform_gather<<<NR, 192, 0, stream>>>(val_bf, ref_buf, off_buf, aw_buf, lvl_buf);
  msdeform_reduce<<<NR / 4, 256, 0, stream>>>(lvl_buf, samp_bf);
  gemm_bf16<false, true, false><<<dim3(NR / 128, 256 / 64), 256, 0, stream>>>(
      (const short*)samp_bf, (const short*)w_op, op_b, out, out, NR, 256, 256);

  // ---- FFN block ----
  ln_kernel<<<NR / 4, 256, 0, stream>>>(out, n3_w, n3_b, q_bf);
  gemm_bf16<true, false, true><<<dim3(NR / 128, 1024 / 64), 256, 0, stream>>>(
      (const short*)q_bf, (const short*)w_l1, l1_b, nullptr, ff1_bf, NR, 1024, 256);
  gemm_bf16<false, true, false><<<dim3(NR / 128, 256 / 64), 256, 0, stream>>>(
      (const short*)ff1_bf, (const short*)w_l2, l2_b, out, out, NR, 256, 1024);
}